// Round 1
// baseline (2675.004 us; speedup 1.0000x reference)
//
#include <hip/hip_runtime.h>
#include <hip/hip_bf16.h>

// Problem: CrossAttention — B=4, Sq=Skv=2048, D=1024, H=16, Dh=64, fp32.
// Round 0: correct fp32 baseline. GEMMs on vector FMA; flash attention 1 wave/block.

#define D_MODEL 1024
#define NHEAD   16
#define DHEAD   64
#define BATCH   4
#define SEQ     2048
#define MROWS   (BATCH * SEQ)   // 8192

// ---------------- fp32 tiled GEMM: C[M,N] = A[M,K] @ W[K,N] (+bias) ----------------
#define BM 128
#define BN 128
#define BKK 16
#define LDT 132   // padded LDS stride (132*4=528 bytes, 16B-aligned rows)

__global__ __launch_bounds__(256) void gemm_f32(const float* __restrict__ A,
                                                const float* __restrict__ W,
                                                const float* __restrict__ bias,
                                                float* __restrict__ C,
                                                int M, int N, int K) {
    __shared__ float As[BKK * LDT];   // [BKK][BM] transposed, padded
    __shared__ float Ws[BKK * LDT];   // [BKK][BN], padded

    const int t  = threadIdx.x;
    const int bm = blockIdx.x;
    const int bn = blockIdx.y;
    const int tx = t & 15;       // 16 cols of threads
    const int ty = t >> 4;       // 16 rows of threads

    float acc[8][8];
#pragma unroll
    for (int i = 0; i < 8; ++i)
#pragma unroll
        for (int j = 0; j < 8; ++j) acc[i][j] = 0.f;

    const float* Ablk = A + (size_t)bm * BM * K;
    const float* Wblk = W + (size_t)bn * BN;

    for (int k0 = 0; k0 < K; k0 += BKK) {
        // ---- stage A tile (128 rows x 16 k), store transposed As[kk][row]
#pragma unroll
        for (int j = 0; j < 2; ++j) {
            int f   = t + 256 * j;          // float4 id, 512 total
            int row = f >> 2;               // 4 float4 per row (16 floats)
            int c4  = f & 3;
            float4 v = *(const float4*)(Ablk + (size_t)row * K + k0 + c4 * 4);
            As[(c4 * 4 + 0) * LDT + row] = v.x;
            As[(c4 * 4 + 1) * LDT + row] = v.y;
            As[(c4 * 4 + 2) * LDT + row] = v.z;
            As[(c4 * 4 + 3) * LDT + row] = v.w;
        }
        // ---- stage W tile (16 k x 128 cols)
#pragma unroll
        for (int j = 0; j < 2; ++j) {
            int f   = t + 256 * j;
            int row = f >> 5;               // 32 float4 per row
            int c4  = f & 31;
            *(float4*)(&Ws[row * LDT + c4 * 4]) =
                *(const float4*)(Wblk + (size_t)(k0 + row) * N + c4 * 4);
        }
        __syncthreads();

#pragma unroll
        for (int kk = 0; kk < BKK; ++kk) {
            float a[8], b[8];
            *(float4*)(a + 0) = *(const float4*)(&As[kk * LDT + ty * 8 + 0]);
            *(float4*)(a + 4) = *(const float4*)(&As[kk * LDT + ty * 8 + 4]);
            *(float4*)(b + 0) = *(const float4*)(&Ws[kk * LDT + tx * 8 + 0]);
            *(float4*)(b + 4) = *(const float4*)(&Ws[kk * LDT + tx * 8 + 4]);
#pragma unroll
            for (int i = 0; i < 8; ++i)
#pragma unroll
                for (int j = 0; j < 8; ++j)
                    acc[i][j] = fmaf(a[i], b[j], acc[i][j]);
        }
        __syncthreads();
    }

    // ---- epilogue
    const int crow0 = bm * BM + ty * 8;
    const int ccol0 = bn * BN + tx * 8;
    float bb[8];
    if (bias) {
#pragma unroll
        for (int j = 0; j < 8; ++j) bb[j] = bias[ccol0 + j];
    } else {
#pragma unroll
        for (int j = 0; j < 8; ++j) bb[j] = 0.f;
    }
#pragma unroll
    for (int i = 0; i < 8; ++i) {
        float4 v0, v1;
        v0.x = acc[i][0] + bb[0]; v0.y = acc[i][1] + bb[1];
        v0.z = acc[i][2] + bb[2]; v0.w = acc[i][3] + bb[3];
        v1.x = acc[i][4] + bb[4]; v1.y = acc[i][5] + bb[5];
        v1.z = acc[i][6] + bb[6]; v1.w = acc[i][7] + bb[7];
        float* cp = C + (size_t)(crow0 + i) * N + ccol0;
        *(float4*)(cp + 0) = v0;
        *(float4*)(cp + 4) = v1;
    }
}

// ---------------- flash attention (fp32), 1 wave/block, 1 q-row/lane ----------------
#define KVT 32

__global__ __launch_bounds__(64) void attn_f32(const float* __restrict__ Q,
                                               const float* __restrict__ K,
                                               const float* __restrict__ V,
                                               float* __restrict__ O) {
    const int b  = blockIdx.z;
    const int h  = blockIdx.y;
    const int qr = blockIdx.x * 64 + threadIdx.x;   // this lane's q row
    const float scale = 0.125f;                     // 1/sqrt(64)

    __shared__ float Ks[KVT][DHEAD];
    __shared__ float Vs[KVT][DHEAD];

    float q[DHEAD], acc[DHEAD];
    const float* qp = Q + ((size_t)(b * SEQ + qr) * D_MODEL) + h * DHEAD;
#pragma unroll
    for (int i = 0; i < 16; ++i) ((float4*)q)[i] = ((const float4*)qp)[i];
#pragma unroll
    for (int d = 0; d < DHEAD; ++d) acc[d] = 0.f;

    float m = -1e30f, l = 0.f;
    const float* Kb = K + ((size_t)b * SEQ * D_MODEL) + h * DHEAD;
    const float* Vb = V + ((size_t)b * SEQ * D_MODEL) + h * DHEAD;

    for (int kv0 = 0; kv0 < SEQ; kv0 += KVT) {
        // ---- stage K/V tile: KVT x 64 each (512 float4 total per matrix)
#pragma unroll
        for (int j = 0; j < 8; ++j) {
            int f   = threadIdx.x + 64 * j;   // 0..511
            int row = f >> 4;                 // 16 float4 per row
            int c4  = f & 15;
            *(float4*)(&Ks[row][c4 * 4]) =
                *(const float4*)(Kb + (size_t)(kv0 + row) * D_MODEL + c4 * 4);
            *(float4*)(&Vs[row][c4 * 4]) =
                *(const float4*)(Vb + (size_t)(kv0 + row) * D_MODEL + c4 * 4);
        }
        __syncthreads();

        float s[KVT];
#pragma unroll
        for (int kk = 0; kk < KVT; ++kk) {
            float sum = 0.f;
#pragma unroll
            for (int i = 0; i < 16; ++i) {
                float4 k4 = ((const float4*)&Ks[kk][0])[i];
                sum = fmaf(q[i * 4 + 0], k4.x, sum);
                sum = fmaf(q[i * 4 + 1], k4.y, sum);
                sum = fmaf(q[i * 4 + 2], k4.z, sum);
                sum = fmaf(q[i * 4 + 3], k4.w, sum);
            }
            s[kk] = sum * scale;
        }

        float mt = m;
#pragma unroll
        for (int kk = 0; kk < KVT; ++kk) mt = fmaxf(mt, s[kk]);
        const float corr = __expf(m - mt);
        float psum = 0.f;
#pragma unroll
        for (int kk = 0; kk < KVT; ++kk) {
            s[kk] = __expf(s[kk] - mt);     // reuse s as p
            psum += s[kk];
        }
        l = l * corr + psum;
        m = mt;
#pragma unroll
        for (int d = 0; d < DHEAD; ++d) acc[d] *= corr;
#pragma unroll
        for (int kk = 0; kk < KVT; ++kk) {
            const float p = s[kk];
#pragma unroll
            for (int i = 0; i < 16; ++i) {
                float4 v4 = ((const float4*)&Vs[kk][0])[i];
                acc[i * 4 + 0] = fmaf(p, v4.x, acc[i * 4 + 0]);
                acc[i * 4 + 1] = fmaf(p, v4.y, acc[i * 4 + 1]);
                acc[i * 4 + 2] = fmaf(p, v4.z, acc[i * 4 + 2]);
                acc[i * 4 + 3] = fmaf(p, v4.w, acc[i * 4 + 3]);
            }
        }
        __syncthreads();
    }

    const float inv = 1.f / l;
    float* op = O + ((size_t)(b * SEQ + qr) * D_MODEL) + h * DHEAD;
#pragma unroll
    for (int i = 0; i < 16; ++i) {
        float4 v;
        v.x = acc[i * 4 + 0] * inv; v.y = acc[i * 4 + 1] * inv;
        v.z = acc[i * 4 + 2] * inv; v.w = acc[i * 4 + 3] * inv;
        ((float4*)op)[i] = v;
    }
}

// ---------------- launch ----------------
extern "C" void kernel_launch(void* const* d_in, const int* in_sizes, int n_in,
                              void* d_out, int out_size, void* d_ws, size_t ws_size,
                              hipStream_t stream) {
    const float* inputs  = (const float*)d_in[0];   // [B,Sq,D]
    const float* context = (const float*)d_in[1];   // [B,Skv,D]
    const float* Wq      = (const float*)d_in[2];   // [D,D]
    const float* Wk      = (const float*)d_in[3];
    const float* Wv      = (const float*)d_in[4];
    const float* Wo      = (const float*)d_in[5];
    const float* bo      = (const float*)d_in[6];   // [D]
    float* out = (float*)d_out;

    const size_t NELEM = (size_t)MROWS * D_MODEL;   // 8388608
    float* Qw = (float*)d_ws;
    float* Kw = Qw + NELEM;
    float* Vw = Kw + NELEM;
    float* Aw = Vw + NELEM;

    dim3 gemm_grid(MROWS / BM, D_MODEL / BN);       // 64 x 8
    dim3 gemm_blk(256);

    gemm_f32<<<gemm_grid, gemm_blk, 0, stream>>>(inputs,  Wq, nullptr, Qw, MROWS, D_MODEL, D_MODEL);
    gemm_f32<<<gemm_grid, gemm_blk, 0, stream>>>(context, Wk, nullptr, Kw, MROWS, D_MODEL, D_MODEL);
    gemm_f32<<<gemm_grid, gemm_blk, 0, stream>>>(context, Wv, nullptr, Vw, MROWS, D_MODEL, D_MODEL);

    dim3 attn_grid(SEQ / 64, NHEAD, BATCH);         // 32 x 16 x 4
    attn_f32<<<attn_grid, dim3(64), 0, stream>>>(Qw, Kw, Vw, Aw);

    gemm_f32<<<gemm_grid, gemm_blk, 0, stream>>>(Aw, Wo, bo, out, MROWS, D_MODEL, D_MODEL);
}

// Round 3
// 1337.196 us; speedup vs baseline: 2.0005x; 2.0005x over previous
//
#include <hip/hip_runtime.h>
#include <hip/hip_bf16.h>

// CrossAttention — B=4, Sq=Skv=2048, D=1024, H=16, Dh=64, fp32 in/out.
// Round 2: fix Vs swizzle overflow ((dv&7)<<3 -> (dv&3)<<3 on 4-slot rows),
//          split P into hi/lo bf16 planes for PV precision.

#define D_MODEL 1024
#define NHEAD   16
#define DHEAD   64
#define BATCH   4
#define SEQ     2048
#define MROWS   (BATCH * SEQ)   // 8192

typedef unsigned short u16;
typedef __attribute__((ext_vector_type(8))) short          bf16x8;  // MFMA A/B frag
typedef __attribute__((ext_vector_type(4))) float          f32x4;   // MFMA C/D frag
typedef __attribute__((ext_vector_type(8))) unsigned short u16x8;   // 16B bf16 vector

__device__ inline u16 f2bf(float x) {            // RNE f32 -> bf16
    unsigned u = __float_as_uint(x);
    u += 0x7fffu + ((u >> 16) & 1u);
    return (u16)(u >> 16);
}
__device__ inline float bf2f(u16 h) { return __uint_as_float(((unsigned)h) << 16); }

__device__ inline f32x4 mfma16(bf16x8 a, bf16x8 b, f32x4 c) {
    return __builtin_amdgcn_mfma_f32_16x16x32_bf16(a, b, c, 0, 0, 0);
}

// ---------------- fp32 tiled GEMM: C[M,N] = A[M,K] @ W[K,N] (+bias) ----------------
// SPLIT_OUT=true: write hi/lo bf16 planes instead of fp32 (for K projection).
#define BM 128
#define BN 128
#define BKK 16
#define LDT 132

template<bool SPLIT_OUT>
__global__ __launch_bounds__(256) void gemm_f32(const float* __restrict__ A,
                                                const float* __restrict__ W,
                                                const float* __restrict__ bias,
                                                float* __restrict__ C,
                                                u16* __restrict__ Chi,
                                                u16* __restrict__ Clo,
                                                int M, int N, int K) {
    __shared__ float As[BKK * LDT];
    __shared__ float Ws[BKK * LDT];

    const int t  = threadIdx.x;
    const int bm = blockIdx.x;
    const int bn = blockIdx.y;
    const int tx = t & 15;
    const int ty = t >> 4;

    float acc[8][8];
#pragma unroll
    for (int i = 0; i < 8; ++i)
#pragma unroll
        for (int j = 0; j < 8; ++j) acc[i][j] = 0.f;

    const float* Ablk = A + (size_t)bm * BM * K;
    const float* Wblk = W + (size_t)bn * BN;

    for (int k0 = 0; k0 < K; k0 += BKK) {
#pragma unroll
        for (int j = 0; j < 2; ++j) {
            int f   = t + 256 * j;
            int row = f >> 2;
            int c4  = f & 3;
            float4 v = *(const float4*)(Ablk + (size_t)row * K + k0 + c4 * 4);
            As[(c4 * 4 + 0) * LDT + row] = v.x;
            As[(c4 * 4 + 1) * LDT + row] = v.y;
            As[(c4 * 4 + 2) * LDT + row] = v.z;
            As[(c4 * 4 + 3) * LDT + row] = v.w;
        }
#pragma unroll
        for (int j = 0; j < 2; ++j) {
            int f   = t + 256 * j;
            int row = f >> 5;
            int c4  = f & 31;
            *(float4*)(&Ws[row * LDT + c4 * 4]) =
                *(const float4*)(Wblk + (size_t)(k0 + row) * N + c4 * 4);
        }
        __syncthreads();

#pragma unroll
        for (int kk = 0; kk < BKK; ++kk) {
            float a[8], b[8];
            *(float4*)(a + 0) = *(const float4*)(&As[kk * LDT + ty * 8 + 0]);
            *(float4*)(a + 4) = *(const float4*)(&As[kk * LDT + ty * 8 + 4]);
            *(float4*)(b + 0) = *(const float4*)(&Ws[kk * LDT + tx * 8 + 0]);
            *(float4*)(b + 4) = *(const float4*)(&Ws[kk * LDT + tx * 8 + 4]);
#pragma unroll
            for (int i = 0; i < 8; ++i)
#pragma unroll
                for (int j = 0; j < 8; ++j)
                    acc[i][j] = fmaf(a[i], b[j], acc[i][j]);
        }
        __syncthreads();
    }

    const int crow0 = bm * BM + ty * 8;
    const int ccol0 = bn * BN + tx * 8;

    if constexpr (SPLIT_OUT) {
#pragma unroll
        for (int i = 0; i < 8; ++i) {
            u16x8 hv, lv;
#pragma unroll
            for (int j = 0; j < 8; ++j) {
                float x = acc[i][j];
                u16 hb = f2bf(x);
                hv[j] = hb;
                lv[j] = f2bf(x - bf2f(hb));
            }
            size_t ro = (size_t)(crow0 + i) * N + ccol0;
            *(u16x8*)(Chi + ro) = hv;
            *(u16x8*)(Clo + ro) = lv;
        }
    } else {
        float bb[8];
        if (bias) {
#pragma unroll
            for (int j = 0; j < 8; ++j) bb[j] = bias[ccol0 + j];
        } else {
#pragma unroll
            for (int j = 0; j < 8; ++j) bb[j] = 0.f;
        }
#pragma unroll
        for (int i = 0; i < 8; ++i) {
            float4 v0, v1;
            v0.x = acc[i][0] + bb[0]; v0.y = acc[i][1] + bb[1];
            v0.z = acc[i][2] + bb[2]; v0.w = acc[i][3] + bb[3];
            v1.x = acc[i][4] + bb[4]; v1.y = acc[i][5] + bb[5];
            v1.z = acc[i][6] + bb[6]; v1.w = acc[i][7] + bb[7];
            float* cp = C + (size_t)(crow0 + i) * N + ccol0;
            *(float4*)(cp + 0) = v0;
            *(float4*)(cp + 4) = v1;
        }
    }
}

// ---------------- V: fp32 [B,S,D] -> transposed split bf16 [B][H][Dh][S] ----------------
__global__ __launch_bounds__(256) void transpose_split(const float* __restrict__ V,
                                                       u16* __restrict__ hi,
                                                       u16* __restrict__ lo) {
    const int b = blockIdx.z, h = blockIdx.y, s0 = blockIdx.x * 64;
    const int t = threadIdx.x;
    __shared__ u16 th[64][72];
    __shared__ u16 tl[64][72];
#pragma unroll
    for (int i = 0; i < 4; ++i) {
        int f  = t + 256 * i;         // 0..1023
        int r  = f >> 4;              // s-row 0..63
        int c4 = f & 15;
        float4 v = *(const float4*)(V + ((size_t)(b * SEQ + s0 + r) * D_MODEL) + h * DHEAD + c4 * 4);
#pragma unroll
        for (int u = 0; u < 4; ++u) {
            int d = c4 * 4 + u;
            float x = ((const float*)&v)[u];
            u16 hb = f2bf(x);
            th[d][r] = hb;
            tl[d][r] = f2bf(x - bf2f(hb));
        }
    }
    __syncthreads();
#pragma unroll
    for (int i = 0; i < 2; ++i) {
        int gidx = t + 256 * i;       // 0..511
        int d = gidx >> 3;
        int c = gidx & 7;
        u16x8 vh, vl;
#pragma unroll
        for (int u = 0; u < 8; ++u) { vh[u] = th[d][c * 8 + u]; vl[u] = tl[d][c * 8 + u]; }
        size_t go = ((size_t)((b * NHEAD + h) * DHEAD + d)) * SEQ + s0 + c * 8;
        *(u16x8*)(hi + go) = vh;
        *(u16x8*)(lo + go) = vl;
    }
}

// ---------------- MFMA flash attention ----------------
// Block: 256 threads = 4 waves; each wave owns 16 q-rows; KV tile = 32 rows.
// QK^T: 3-way split-bf16 (hi*hi + hi*lo + lo*hi), fp32 accum.
// PV:   P split hi/lo (p_hi*V_hi + p_hi*V_lo + p_lo*V_hi), fp32 denominator.
#define QT  64
#define KVT 32

__global__ __launch_bounds__(256) void attn_mfma(const float* __restrict__ Q,
                                                 const u16* __restrict__ Khi,
                                                 const u16* __restrict__ Klo,
                                                 const u16* __restrict__ Vthi,
                                                 const u16* __restrict__ Vtlo,
                                                 float* __restrict__ O) {
    const int b = blockIdx.z, h = blockIdx.y, qt = blockIdx.x;
    const int t  = threadIdx.x;
    const int w  = t >> 6;
    const int l  = t & 63;
    const int g  = l >> 4;     // lanegroup 0..3
    const int lr = l & 15;

    __shared__ u16 Ks[2][KVT * DHEAD];    // [hi/lo][row*64+d]  swizzle: ^((row&7)<<3), 8 slots/row
    __shared__ u16 Vs[2][DHEAD * KVT];    // [hi/lo][d*32+k]    swizzle: ^((d&3)<<3),  4 slots/row
    __shared__ u16 Pl[4][2][16 * 32];     // per-wave P hi/lo   swizzle: ^((q&3)<<3),  4 slots/row

    // ---- Q A-frags (pre-scaled by 1/sqrt(Dh)), split hi/lo; lane row = lr
    bf16x8 qhi[2], qlo[2];
    {
        const int qrow = qt * QT + w * 16 + lr;
        const float* qp = Q + ((size_t)(b * SEQ + qrow) * D_MODEL) + h * DHEAD;
#pragma unroll
        for (int c = 0; c < 2; ++c) {
            float tmp[8];
            *(float4*)(tmp)     = *(const float4*)(qp + 32 * c + 8 * g);
            *(float4*)(tmp + 4) = *(const float4*)(qp + 32 * c + 8 * g + 4);
#pragma unroll
            for (int j = 0; j < 8; ++j) {
                float x = tmp[j] * 0.125f;
                u16 hb = f2bf(x);
                qhi[c][j] = (short)hb;
                qlo[c][j] = (short)f2bf(x - bf2f(hb));
            }
        }
    }

    f32x4 o[4];
#pragma unroll
    for (int c = 0; c < 4; ++c) o[c] = (f32x4){0.f, 0.f, 0.f, 0.f};
    float mrow[4], lrow[4];
#pragma unroll
    for (int j = 0; j < 4; ++j) { mrow[j] = -1e30f; lrow[j] = 0.f; }

    const u16* Kh = Khi + ((size_t)(b * SEQ) * D_MODEL) + h * DHEAD;
    const u16* Kl = Klo + ((size_t)(b * SEQ) * D_MODEL) + h * DHEAD;
    const u16* Vh = Vthi + ((size_t)(b * NHEAD + h) * DHEAD) * SEQ;
    const u16* Vl = Vtlo + ((size_t)(b * NHEAD + h) * DHEAD) * SEQ;

    for (int kv0 = 0; kv0 < SEQ; kv0 += KVT) {
        // ---- stage K (32x64) and V^T (64x32), hi+lo, b128 everywhere
        {
            int row = t >> 3, d0 = (t & 7) * 8;
            size_t gofs = (size_t)(kv0 + row) * D_MODEL + d0;
            int kph = row * 64 + (d0 ^ ((row & 7) << 3));
            *(u16x8*)&Ks[0][kph] = *(const u16x8*)(Kh + gofs);
            *(u16x8*)&Ks[1][kph] = *(const u16x8*)(Kl + gofs);

            int dv = t >> 2, kk0 = (t & 3) * 8;
            size_t vofs = (size_t)dv * SEQ + kv0 + kk0;
            int vph = dv * 32 + (kk0 ^ ((dv & 3) << 3));   // FIXED: &3 (4 slots/row)
            *(u16x8*)&Vs[0][vph] = *(const u16x8*)(Vh + vofs);
            *(u16x8*)&Vs[1][vph] = *(const u16x8*)(Vl + vofs);
        }
        __syncthreads();

        // ---- QK^T: S[16q x 32k], two 16x16 halves, 12 MFMAs
        f32x4 s0 = (f32x4){0.f, 0.f, 0.f, 0.f};
        f32x4 s1 = (f32x4){0.f, 0.f, 0.f, 0.f};
#pragma unroll
        for (int c = 0; c < 2; ++c) {
            int d0 = 8 * g + 32 * c;
            int r0 = lr, r1 = lr + 16;
            int p0 = r0 * 64 + (d0 ^ ((r0 & 7) << 3));
            int p1 = r1 * 64 + (d0 ^ ((r1 & 7) << 3));
            bf16x8 k0h = *(const bf16x8*)&Ks[0][p0];
            bf16x8 k0l = *(const bf16x8*)&Ks[1][p0];
            bf16x8 k1h = *(const bf16x8*)&Ks[0][p1];
            bf16x8 k1l = *(const bf16x8*)&Ks[1][p1];
            s0 = mfma16(qhi[c], k0h, s0);
            s0 = mfma16(qhi[c], k0l, s0);
            s0 = mfma16(qlo[c], k0h, s0);
            s1 = mfma16(qhi[c], k1h, s1);
            s1 = mfma16(qhi[c], k1l, s1);
            s1 = mfma16(qlo[c], k1h, s1);
        }

        // ---- online softmax (lane holds S[q=4g+j][k=lr(+16)], j=0..3)
        float mx[4], corr[4], rs[4];
#pragma unroll
        for (int j = 0; j < 4; ++j) mx[j] = fmaxf(s0[j], s1[j]);
#pragma unroll
        for (int off = 1; off < 16; off <<= 1)
#pragma unroll
            for (int j = 0; j < 4; ++j) mx[j] = fmaxf(mx[j], __shfl_xor(mx[j], off));
#pragma unroll
        for (int j = 0; j < 4; ++j) {
            float mn = fmaxf(mrow[j], mx[j]);
            corr[j] = __expf(mrow[j] - mn);
            mrow[j] = mn;
            s0[j] = __expf(s0[j] - mn);
            s1[j] = __expf(s1[j] - mn);
            rs[j] = s0[j] + s1[j];
        }
#pragma unroll
        for (int off = 1; off < 16; off <<= 1)
#pragma unroll
            for (int j = 0; j < 4; ++j) rs[j] += __shfl_xor(rs[j], off);
#pragma unroll
        for (int j = 0; j < 4; ++j) lrow[j] = lrow[j] * corr[j] + rs[j];
#pragma unroll
        for (int c = 0; c < 4; ++c)
#pragma unroll
            for (int j = 0; j < 4; ++j) o[c][j] *= corr[j];

        // ---- P -> bf16 hi/lo -> LDS (per-wave), read back as A-frags
#pragma unroll
        for (int j = 0; j < 4; ++j) {
            int q0 = 4 * g + j;
            int sw = (q0 & 3) << 3;
            u16 h0 = f2bf(s0[j]);
            u16 h1 = f2bf(s1[j]);
            Pl[w][0][q0 * 32 + (lr ^ sw)]        = h0;
            Pl[w][0][q0 * 32 + ((lr + 16) ^ sw)] = h1;
            Pl[w][1][q0 * 32 + (lr ^ sw)]        = f2bf(s0[j] - bf2f(h0));
            Pl[w][1][q0 * 32 + ((lr + 16) ^ sw)] = f2bf(s1[j] - bf2f(h1));
        }
        const int prd = lr * 32 + ((8 * g) ^ ((lr & 3) << 3));
        bf16x8 pah = *(const bf16x8*)&Pl[w][0][prd];
        bf16x8 pal = *(const bf16x8*)&Pl[w][1][prd];

        // ---- PV: O[16q x 64d] += Phi*(Vhi+Vlo) + Plo*Vhi, 12 MFMAs
#pragma unroll
        for (int c = 0; c < 4; ++c) {
            int dv = 16 * c + lr;
            int vp = dv * 32 + ((8 * g) ^ ((dv & 3) << 3));   // FIXED: &3
            bf16x8 vbh = *(const bf16x8*)&Vs[0][vp];
            bf16x8 vbl = *(const bf16x8*)&Vs[1][vp];
            o[c] = mfma16(pah, vbh, o[c]);
            o[c] = mfma16(pah, vbl, o[c]);
            o[c] = mfma16(pal, vbh, o[c]);
        }
        __syncthreads();
    }

    // ---- epilogue: O row = 4g+j, col = 16c+lr
    const int qrow0 = qt * QT + w * 16;
#pragma unroll
    for (int j = 0; j < 4; ++j) {
        float inv = 1.f / lrow[j];
        int row = qrow0 + 4 * g + j;
        float* op = O + ((size_t)(b * SEQ + row)) * D_MODEL + h * DHEAD;
#pragma unroll
        for (int c = 0; c < 4; ++c)
            op[16 * c + lr] = o[c][j] * inv;
    }
}

// ---------------- launch ----------------
extern "C" void kernel_launch(void* const* d_in, const int* in_sizes, int n_in,
                              void* d_out, int out_size, void* d_ws, size_t ws_size,
                              hipStream_t stream) {
    const float* inputs  = (const float*)d_in[0];
    const float* context = (const float*)d_in[1];
    const float* Wq      = (const float*)d_in[2];
    const float* Wk      = (const float*)d_in[3];
    const float* Wv      = (const float*)d_in[4];
    const float* Wo      = (const float*)d_in[5];
    const float* bo      = (const float*)d_in[6];
    float* out = (float*)d_out;

    const size_t NELEM = (size_t)MROWS * D_MODEL;   // 8.39M
    float* Qw  = (float*)d_ws;            // 32 MB
    float* Aw  = Qw + NELEM;              // 32 MB (V fp32 temp, then attn out)
    u16*   Khi = (u16*)(Aw + NELEM);      // 16 MB
    u16*   Klo = Khi + NELEM;             // 16 MB
    u16*   Vthi = Klo + NELEM;            // 16 MB
    u16*   Vtlo = Vthi + NELEM;           // 16 MB  -> 128 MB total

    dim3 gg(MROWS / BM, D_MODEL / BN);
    dim3 gb(256);

    gemm_f32<false><<<gg, gb, 0, stream>>>(inputs,  Wq, nullptr, Qw, nullptr, nullptr,
                                           MROWS, D_MODEL, D_MODEL);
    gemm_f32<true ><<<gg, gb, 0, stream>>>(context, Wk, nullptr, nullptr, Khi, Klo,
                                           MROWS, D_MODEL, D_MODEL);
    gemm_f32<false><<<gg, gb, 0, stream>>>(context, Wv, nullptr, Aw, nullptr, nullptr,
                                           MROWS, D_MODEL, D_MODEL);
    transpose_split<<<dim3(SEQ / 64, NHEAD, BATCH), gb, 0, stream>>>(Aw, Vthi, Vtlo);
    attn_mfma<<<dim3(SEQ / QT, NHEAD, BATCH), gb, 0, stream>>>(Qw, Khi, Klo, Vthi, Vtlo, Aw);
    gemm_f32<false><<<gg, gb, 0, stream>>>(Aw, Wo, bo, out, nullptr, nullptr,
                                           MROWS, D_MODEL, D_MODEL);
}

// Round 4
// 588.026 us; speedup vs baseline: 4.5491x; 2.2740x over previous
//
#include <hip/hip_runtime.h>
#include <hip/hip_bf16.h>

// CrossAttention — B=4, Sq=Skv=2048, D=1024, H=16, Dh=64, fp32 in/out.
// Round 3: all four GEMMs -> split-bf16 (hi/lo) MFMA with global_load_lds staging;
//          attention -> swapped QK^T (S^T = K*Q) so P stays in registers (no P-LDS,
//          no shuffle storm), k-slot permutation baked into Vs staging.
// Workspace: 117 MB (<128 MB proven), heavy buffer aliasing (see kernel_launch).

#define D_MODEL 1024
#define NHEAD   16
#define DHEAD   64
#define BATCH   4
#define SEQ     2048
#define MROWS   (BATCH * SEQ)   // 8192

typedef unsigned short u16;
typedef __attribute__((ext_vector_type(8))) short          bf16x8;
typedef __attribute__((ext_vector_type(4))) float          f32x4;
typedef __attribute__((ext_vector_type(8))) unsigned short u16x8;
typedef __attribute__((ext_vector_type(4))) unsigned short u16x4;

__device__ __forceinline__ u16 f2bf(float x) {          // RNE f32 -> bf16
    unsigned u = __float_as_uint(x);
    u += 0x7fffu + ((u >> 16) & 1u);
    return (u16)(u >> 16);
}
__device__ __forceinline__ float bf2f(u16 h) { return __uint_as_float(((unsigned)h) << 16); }

__device__ __forceinline__ f32x4 mfma16(bf16x8 a, bf16x8 b, f32x4 c) {
    return __builtin_amdgcn_mfma_f32_16x16x32_bf16(a, b, c, 0, 0, 0);
}

// async global->LDS, 16B per lane; LDS dest must be linear (wave base + lane*16)
__device__ __forceinline__ void glds16(const void* g, void* l) {
    __builtin_amdgcn_global_load_lds(
        (const __attribute__((address_space(1))) void*)g,
        (__attribute__((address_space(3))) void*)l, 16, 0, 0);
}

// ---------------- elementwise fp32 -> bf16 hi/lo planes ----------------
__global__ __launch_bounds__(256) void split_f32(const float* __restrict__ x,
                                                 u16* __restrict__ hi,
                                                 u16* __restrict__ lo) {
    size_t i = ((size_t)blockIdx.x * 256 + threadIdx.x) * 8;
    float4 a = *(const float4*)(x + i);
    float4 b = *(const float4*)(x + i + 4);
    float v[8] = {a.x, a.y, a.z, a.w, b.x, b.y, b.z, b.w};
    u16x8 h, l;
#pragma unroll
    for (int u = 0; u < 8; ++u) {
        u16 hb = f2bf(v[u]);
        h[u] = hb;
        l[u] = f2bf(v[u] - bf2f(hb));
    }
    *(u16x8*)(hi + i) = h;
    *(u16x8*)(lo + i) = l;
}

// ---------------- W [K=1024][N=1024] fp32 -> WT hi/lo [N][K] bf16 ----------------
__global__ __launch_bounds__(256) void wtrans(const float* __restrict__ W,
                                              u16* __restrict__ Thi,
                                              u16* __restrict__ Tlo) {
    const int k0 = blockIdx.x * 64, n0 = blockIdx.y * 64;
    const int t = threadIdx.x;
    __shared__ u16 th[64 * 64];
    __shared__ u16 tl[64 * 64];
#pragma unroll
    for (int rep = 0; rep < 4; ++rep) {
        int kr = (t >> 4) + 16 * rep;
        int nc = (t & 15) * 4;
        float4 v = *(const float4*)(W + (size_t)(k0 + kr) * D_MODEL + n0 + nc);
#pragma unroll
        for (int u = 0; u < 4; ++u) {
            int n = nc + u;
            float x = ((const float*)&v)[u];
            u16 hb = f2bf(x);
            int a = n * 64 + (kr ^ (8 * ((n >> 3) & 7)));
            th[a] = hb;
            tl[a] = f2bf(x - bf2f(hb));
        }
    }
    __syncthreads();
#pragma unroll
    for (int rep = 0; rep < 2; ++rep) {
        int n = (t >> 3) + 32 * rep;
        int kb = (t & 7) * 8;
        int a = n * 64 + (kb ^ (8 * ((n >> 3) & 7)));
        size_t go = (size_t)(n0 + n) * D_MODEL + k0 + kb;
        *(u16x8*)(Thi + go) = *(const u16x8*)&th[a];
        *(u16x8*)(Tlo + go) = *(const u16x8*)&tl[a];
    }
}

// ---------------- V planes [M][1024] -> Vt planes [B][H][64][S] ----------------
__global__ __launch_bounds__(256) void vtrans(const u16* __restrict__ Vhi,
                                              const u16* __restrict__ Vlo,
                                              u16* __restrict__ Thi,
                                              u16* __restrict__ Tlo) {
    const int b = blockIdx.z, h = blockIdx.y, s0 = blockIdx.x * 64;
    const int t = threadIdx.x;
    __shared__ u16 th[64 * 64];
    __shared__ u16 tl[64 * 64];
#pragma unroll
    for (int rep = 0; rep < 2; ++rep) {
        int s = (t >> 3) + 32 * rep;
        int db = (t & 7) * 8;
        size_t go = (size_t)(b * SEQ + s0 + s) * D_MODEL + h * DHEAD + db;
        u16x8 vh = *(const u16x8*)(Vhi + go);
        u16x8 vl = *(const u16x8*)(Vlo + go);
#pragma unroll
        for (int u = 0; u < 8; ++u) {
            int d = db + u;
            int a = d * 64 + (s ^ (8 * ((d >> 3) & 7)));
            th[a] = vh[u];
            tl[a] = vl[u];
        }
    }
    __syncthreads();
#pragma unroll
    for (int rep = 0; rep < 2; ++rep) {
        int d = (t >> 3) + 32 * rep;
        int sb = (t & 7) * 8;
        int a = d * 64 + (sb ^ (8 * ((d >> 3) & 7)));
        size_t go = ((size_t)((b * NHEAD + h) * DHEAD + d)) * SEQ + s0 + sb;
        *(u16x8*)(Thi + go) = *(const u16x8*)&th[a];
        *(u16x8*)(Tlo + go) = *(const u16x8*)&tl[a];
    }
}

// ---------------- split-bf16 MFMA GEMM: C[M=8192][N=1024] = A @ W (+bias) ----------------
// AMODE 0: A given as bf16 hi/lo planes [M][K]; AMODE 1: A fp32 [M][K], split in staging.
// EPI 0: fp32 out + bias; EPI 1: bf16 hi/lo plane out.
// 128x128 tile, BK=32, 4 waves (each 64x64), C = Ahi*Bhi + Ahi*Blo + Alo*Bhi.
template<int AMODE, int EPI>
__global__ __launch_bounds__(256) void gemm3p(const u16* __restrict__ Ahi,
                                              const u16* __restrict__ Alo,
                                              const float* __restrict__ Af,
                                              const u16* __restrict__ Bhi,
                                              const u16* __restrict__ Blo,
                                              const float* __restrict__ bias,
                                              float* __restrict__ Cf,
                                              u16* __restrict__ Chi,
                                              u16* __restrict__ Clo) {
    const int K = 1024, N = 1024;
    __shared__ u16 sA[2][128 * 32];
    __shared__ u16 sB[2][128 * 32];

    const int t = threadIdx.x;
    const int w = t >> 6, l = t & 63, g = l >> 4, lr = l & 15;
    const int wrow = (w >> 1) * 64, wcol = (w & 1) * 64;

    // XCD-chunked swizzle: 512 blocks, 8 XCDs -> each XCD gets 8 bm-rows x all 8 bn
    const int bid = blockIdx.x;
    const int wg = (bid & 7) * 64 + (bid >> 3);
    const int bm = wg >> 3, bn = wg & 7;

    f32x4 acc[4][4];
#pragma unroll
    for (int i = 0; i < 4; ++i)
#pragma unroll
        for (int j = 0; j < 4; ++j) acc[i][j] = (f32x4){0.f, 0.f, 0.f, 0.f};

    const int srow = t >> 2;        // 0..63
    const int scg  = (t & 3) * 8;   // k-offset within tile

    for (int k0 = 0; k0 < K; k0 += 32) {
#pragma unroll
        for (int rep = 0; rep < 2; ++rep) {
            const int row  = srow + 64 * rep;
            const int lofs = row * 32 + scg;
            const size_t ga = (size_t)(bm * 128 + row) * K + k0 + scg;
            if constexpr (AMODE == 0) {
                glds16(Ahi + ga, &sA[0][lofs]);
                glds16(Alo + ga, &sA[1][lofs]);
            } else {
                float4 va = *(const float4*)(Af + ga);
                float4 vb = *(const float4*)(Af + ga + 4);
                float vv[8] = {va.x, va.y, va.z, va.w, vb.x, vb.y, vb.z, vb.w};
                u16x8 hv, lv;
#pragma unroll
                for (int u = 0; u < 8; ++u) {
                    u16 hb = f2bf(vv[u]);
                    hv[u] = hb;
                    lv[u] = f2bf(vv[u] - bf2f(hb));
                }
                *(u16x8*)&sA[0][lofs] = hv;
                *(u16x8*)&sA[1][lofs] = lv;
            }
            const size_t gb = (size_t)(bn * 128 + row) * K + k0 + scg;
            glds16(Bhi + gb, &sB[0][lofs]);
            glds16(Blo + gb, &sB[1][lofs]);
        }
        __syncthreads();

        bf16x8 ah[4], al[4], bh[4], bl[4];
#pragma unroll
        for (int f = 0; f < 4; ++f) {
            const int ra = (wrow + f * 16 + lr) * 32 + 8 * g;
            ah[f] = *(const bf16x8*)&sA[0][ra];
            al[f] = *(const bf16x8*)&sA[1][ra];
            const int rb = (wcol + f * 16 + lr) * 32 + 8 * g;
            bh[f] = *(const bf16x8*)&sB[0][rb];
            bl[f] = *(const bf16x8*)&sB[1][rb];
        }
#pragma unroll
        for (int fi = 0; fi < 4; ++fi)
#pragma unroll
            for (int fj = 0; fj < 4; ++fj) {
                acc[fi][fj] = mfma16(ah[fi], bh[fj], acc[fi][fj]);
                acc[fi][fj] = mfma16(ah[fi], bl[fj], acc[fi][fj]);
                acc[fi][fj] = mfma16(al[fi], bh[fj], acc[fi][fj]);
            }
        __syncthreads();
    }

#pragma unroll
    for (int fj = 0; fj < 4; ++fj) {
        const int colg = bn * 128 + wcol + fj * 16 + lr;
        float bv = 0.f;
        if constexpr (EPI == 0) bv = bias[colg];
#pragma unroll
        for (int fi = 0; fi < 4; ++fi) {
            const int rowb = bm * 128 + wrow + fi * 16 + 4 * g;
#pragma unroll
            for (int j = 0; j < 4; ++j) {
                const float v = acc[fi][fj][j];
                const size_t co = (size_t)(rowb + j) * N + colg;
                if constexpr (EPI == 0) {
                    Cf[co] = v + bv;
                } else {
                    u16 hb = f2bf(v);
                    Chi[co] = hb;
                    Clo[co] = f2bf(v - bf2f(hb));
                }
            }
        }
    }
}

// ---------------- MFMA flash attention, swapped QK^T, in-register P ----------------
// 256 thr = 4 waves, 16 q-rows/wave, KV tile 32. Lane: q = lr (fixed), holds
// S^T[k = 4g+j (+16)][q] after mfma(K, Q). k-slot permutation pi baked into Vs:
// slot 8g+i <-> k = 4g+i (i<4), slot 8g+4+i <-> k = 16+4g+i, so the packed P regs
// feed PV's B operand directly (zero cross-lane traffic).
__global__ __launch_bounds__(256) void attn_mfma2(const u16* __restrict__ Qhi,
                                                  const u16* __restrict__ Qlo,
                                                  const u16* __restrict__ Khi,
                                                  const u16* __restrict__ Klo,
                                                  const u16* __restrict__ Vthi,
                                                  const u16* __restrict__ Vtlo,
                                                  u16* __restrict__ Ahi,
                                                  u16* __restrict__ Alo) {
    const int b = blockIdx.z, h = blockIdx.y, qt = blockIdx.x;
    const int t = threadIdx.x, w = t >> 6, l = t & 63, g = l >> 4, lr = l & 15;

    __shared__ u16 Ks[2][32 * 64];   // [hi/lo][krow*64 + d], d ^ ((krow&7)<<3)
    __shared__ u16 Vs[2][64 * 32];   // [hi/lo][d*32 + slot], slot ^ ((d&3)<<3), pi-permuted

    const int qrow = qt * 64 + w * 16 + lr;
    const size_t qbase = (size_t)(b * SEQ + qrow) * D_MODEL + h * DHEAD;
    bf16x8 qh[2], ql[2];
#pragma unroll
    for (int c = 0; c < 2; ++c) {
        qh[c] = *(const bf16x8*)(Qhi + qbase + 32 * c + 8 * g);
        ql[c] = *(const bf16x8*)(Qlo + qbase + 32 * c + 8 * g);
    }

    f32x4 o[4];
#pragma unroll
    for (int c = 0; c < 4; ++c) o[c] = (f32x4){0.f, 0.f, 0.f, 0.f};
    float m = -1e30f, lsum = 0.f;

    const u16* Kh = Khi + (size_t)(b * SEQ) * D_MODEL + h * DHEAD;
    const u16* Kl = Klo + (size_t)(b * SEQ) * D_MODEL + h * DHEAD;
    const size_t vbase = (size_t)((b * NHEAD + h) * DHEAD) * SEQ;

    // staging coordinates (constant per thread)
    const int krow = t >> 3, kd0 = (t & 7) * 8;
    const int kph = krow * 64 + (kd0 ^ ((krow & 7) << 3));
    const int vdv = t >> 2, vm = t & 3;
    const int sb0 = (vm & 1) * 16 + (vm >> 1) * 4;   // pi: slot base for actual k = 8*vm
    const int vp0 = vdv * 32 + (sb0 ^ ((vdv & 3) << 3));
    const int vp1 = vdv * 32 + ((sb0 + 8) ^ ((vdv & 3) << 3));

    for (int kv0 = 0; kv0 < SEQ; kv0 += 32) {
        // ---- stage K (32x64) and V^T (64x32, pi-permuted slots)
        const size_t kg = (size_t)(kv0 + krow) * D_MODEL + kd0;
        *(u16x8*)&Ks[0][kph] = *(const u16x8*)(Kh + kg);
        *(u16x8*)&Ks[1][kph] = *(const u16x8*)(Kl + kg);
        const size_t vg = vbase + (size_t)vdv * SEQ + kv0 + vm * 8;
        u16x8 vh8 = *(const u16x8*)(Vthi + vg);
        u16x8 vl8 = *(const u16x8*)(Vtlo + vg);
        *(u16x4*)&Vs[0][vp0] = (u16x4){vh8[0], vh8[1], vh8[2], vh8[3]};
        *(u16x4*)&Vs[0][vp1] = (u16x4){vh8[4], vh8[5], vh8[6], vh8[7]};
        *(u16x4*)&Vs[1][vp0] = (u16x4){vl8[0], vl8[1], vl8[2], vl8[3]};
        *(u16x4*)&Vs[1][vp1] = (u16x4){vl8[4], vl8[5], vl8[6], vl8[7]};
        __syncthreads();

        // ---- S^T = K * Q (12 MFMAs, 3-plane split)
        f32x4 sl = (f32x4){0.f, 0.f, 0.f, 0.f};
        f32x4 sh = (f32x4){0.f, 0.f, 0.f, 0.f};
#pragma unroll
        for (int c = 0; c < 2; ++c) {
            const int d0 = 8 * g + 32 * c;
            const int p0 = lr * 64 + (d0 ^ ((lr & 7) << 3));
            const int p1 = (lr + 16) * 64 + (d0 ^ ((lr & 7) << 3));
            bf16x8 k0h = *(const bf16x8*)&Ks[0][p0];
            bf16x8 k0l = *(const bf16x8*)&Ks[1][p0];
            bf16x8 k1h = *(const bf16x8*)&Ks[0][p1];
            bf16x8 k1l = *(const bf16x8*)&Ks[1][p1];
            sl = mfma16(k0h, qh[c], sl);
            sl = mfma16(k0h, ql[c], sl);
            sl = mfma16(k0l, qh[c], sl);
            sh = mfma16(k1h, qh[c], sh);
            sh = mfma16(k1h, ql[c], sh);
            sh = mfma16(k1l, qh[c], sh);
        }
#pragma unroll
        for (int j = 0; j < 4; ++j) { sl[j] *= 0.125f; sh[j] *= 0.125f; }

        // ---- online softmax: q is lane-local; reduce across 4 lane-groups only
        float mx = fmaxf(fmaxf(fmaxf(sl[0], sl[1]), fmaxf(sl[2], sl[3])),
                         fmaxf(fmaxf(sh[0], sh[1]), fmaxf(sh[2], sh[3])));
        mx = fmaxf(mx, __shfl_xor(mx, 16));
        mx = fmaxf(mx, __shfl_xor(mx, 32));
        const float mn = fmaxf(m, mx);
        const float corr = __expf(m - mn);
        m = mn;
#pragma unroll
        for (int j = 0; j < 4; ++j) {
            sl[j] = __expf(sl[j] - mn);
            sh[j] = __expf(sh[j] - mn);
        }
        float rs = (sl[0] + sl[1]) + (sl[2] + sl[3]) + (sh[0] + sh[1]) + (sh[2] + sh[3]);
        rs += __shfl_xor(rs, 16);
        rs += __shfl_xor(rs, 32);
        lsum = lsum * corr + rs;
#pragma unroll
        for (int c = 0; c < 4; ++c)
#pragma unroll
            for (int j = 0; j < 4; ++j) o[c][j] *= corr;

        // ---- P hi/lo packed in-register (matches pi slot order)
        bf16x8 pbh, pbl;
#pragma unroll
        for (int j = 0; j < 4; ++j) {
            u16 h0 = f2bf(sl[j]);
            pbh[j] = (short)h0;
            pbl[j] = (short)f2bf(sl[j] - bf2f(h0));
            u16 h1 = f2bf(sh[j]);
            pbh[4 + j] = (short)h1;
            pbl[4 + j] = (short)f2bf(sh[j] - bf2f(h1));
        }

        // ---- O^T += V^T * P^T (12 MFMAs)
#pragma unroll
        for (int c = 0; c < 4; ++c) {
            const int dv = 16 * c + lr;
            const int vp = dv * 32 + ((8 * g) ^ ((dv & 3) << 3));
            bf16x8 vbh = *(const bf16x8*)&Vs[0][vp];
            bf16x8 vbl = *(const bf16x8*)&Vs[1][vp];
            o[c] = mfma16(vbh, pbh, o[c]);
            o[c] = mfma16(vbl, pbh, o[c]);
            o[c] = mfma16(vbh, pbl, o[c]);
        }
        __syncthreads();
    }

    // ---- epilogue: lane q = lr, d = 16c + 4g + j -> split bf16 planes
    const float inv = 1.f / lsum;
#pragma unroll
    for (int c = 0; c < 4; ++c) {
        u16x4 hv, lv;
#pragma unroll
        for (int j = 0; j < 4; ++j) {
            const float v = o[c][j] * inv;
            const u16 hb = f2bf(v);
            hv[j] = hb;
            lv[j] = f2bf(v - bf2f(hb));
        }
        const size_t ao = qbase + 16 * c + 4 * g;
        *(u16x4*)(Ahi + ao) = hv;
        *(u16x4*)(Alo + ao) = lv;
    }
}

// ---------------- launch ----------------
extern "C" void kernel_launch(void* const* d_in, const int* in_sizes, int n_in,
                              void* d_out, int out_size, void* d_ws, size_t ws_size,
                              hipStream_t stream) {
    const float* inputs  = (const float*)d_in[0];
    const float* context = (const float*)d_in[1];
    const float* Wq      = (const float*)d_in[2];
    const float* Wk      = (const float*)d_in[3];
    const float* Wv      = (const float*)d_in[4];
    const float* Wo      = (const float*)d_in[5];
    const float* bo      = (const float*)d_in[6];
    float* out = (float*)d_out;

    const size_t P  = (size_t)MROWS * D_MODEL;      // 8388608 elems
    const size_t WP = (size_t)D_MODEL * D_MODEL;    // 1048576 elems

    u16* base = (u16*)d_ws;
    // r0: Ctx hi/lo -> Vt hi/lo       (2P)
    u16* r0 = base;
    // r1: K hi/lo                      (2P)
    u16* r1 = base + 2 * P;
    // r2: V hi/lo -> Q hi/lo -> A hi/lo (2P)
    u16* r2 = base + 4 * P;
    // W planes: WkT, WvT, WqT, WoT hi/lo (8 * WP)
    u16* wt = base + 6 * P;
    u16 *wkh = wt,          *wkl = wt + WP;
    u16 *wvh = wt + 2 * WP, *wvl = wt + 3 * WP;
    u16 *wqh = wt + 4 * WP, *wql = wt + 5 * WP;
    u16 *woh = wt + 6 * WP, *wol = wt + 7 * WP;

    u16 *ctxh = r0, *ctxl = r0 + P;
    u16 *vth  = r0, *vtl  = r0 + P;   // after ctx dead
    u16 *kh   = r1, *kl   = r1 + P;
    u16 *vh   = r2, *vl   = r2 + P;
    u16 *qh   = r2, *ql   = r2 + P;   // after v dead (Q over V)
    u16 *ah   = r2, *al   = r2 + P;   // attn writes A over Q (per-block read-before-write)

    dim3 tb(256);
    dim3 wg_grid(16, 16);

    wtrans<<<wg_grid, tb, 0, stream>>>(Wk, wkh, wkl);
    wtrans<<<wg_grid, tb, 0, stream>>>(Wv, wvh, wvl);
    wtrans<<<wg_grid, tb, 0, stream>>>(Wq, wqh, wql);
    wtrans<<<wg_grid, tb, 0, stream>>>(Wo, woh, wol);

    split_f32<<<dim3(P / (256 * 8)), tb, 0, stream>>>(context, ctxh, ctxl);

    gemm3p<0, 1><<<dim3(512), tb, 0, stream>>>(ctxh, ctxl, nullptr, wkh, wkl,
                                               nullptr, nullptr, kh, kl);
    gemm3p<0, 1><<<dim3(512), tb, 0, stream>>>(ctxh, ctxl, nullptr, wvh, wvl,
                                               nullptr, nullptr, vh, vl);

    vtrans<<<dim3(SEQ / 64, NHEAD, BATCH), tb, 0, stream>>>(vh, vl, vth, vtl);

    gemm3p<1, 1><<<dim3(512), tb, 0, stream>>>(nullptr, nullptr, inputs, wqh, wql,
                                               nullptr, nullptr, qh, ql);

    attn_mfma2<<<dim3(SEQ / 64, NHEAD, BATCH), tb, 0, stream>>>(qh, ql, kh, kl,
                                                                vth, vtl, ah, al);

    gemm3p<0, 0><<<dim3(512), tb, 0, stream>>>(ah, al, nullptr, woh, wol,
                                               bo, out, nullptr, nullptr);
}

// Round 5
// 539.025 us; speedup vs baseline: 4.9627x; 1.0909x over previous
//
#include <hip/hip_runtime.h>
#include <hip/hip_bf16.h>

// CrossAttention — B=4, Sq=Skv=2048, D=1024, H=16, Dh=64, fp32 in/out.
// Round 4: attention VALU diet — KVT=64, glds K-staging (pre-swizzled source),
//          v_cvt_pk_bf16_f32 P-pack, defer-rescale (T13), exp2-units folded into Wq.

#define D_MODEL 1024
#define NHEAD   16
#define DHEAD   64
#define BATCH   4
#define SEQ     2048
#define MROWS   (BATCH * SEQ)   // 8192

typedef unsigned short u16;
typedef __attribute__((ext_vector_type(8))) short          bf16x8;
typedef __attribute__((ext_vector_type(4))) float          f32x4;
typedef __attribute__((ext_vector_type(8))) unsigned short u16x8;
typedef __attribute__((ext_vector_type(4))) unsigned short u16x4;

__device__ __forceinline__ u16 f2bf(float x) {          // RNE f32 -> bf16
    unsigned u = __float_as_uint(x);
    u += 0x7fffu + ((u >> 16) & 1u);
    return (u16)(u >> 16);
}
__device__ __forceinline__ float bf2f(u16 h) { return __uint_as_float(((unsigned)h) << 16); }

__device__ __forceinline__ f32x4 mfma16(bf16x8 a, bf16x8 b, f32x4 c) {
    return __builtin_amdgcn_mfma_f32_16x16x32_bf16(a, b, c, 0, 0, 0);
}

__device__ __forceinline__ float exp2fast(float x) {    // D = 2^S0
    float r;
    asm("v_exp_f32 %0, %1" : "=v"(r) : "v"(x));
    return r;
}

// async global->LDS, 16B per lane; LDS dest must be linear (wave base + lane*16)
__device__ __forceinline__ void glds16(const void* g, void* l) {
    __builtin_amdgcn_global_load_lds(
        (const __attribute__((address_space(1))) void*)g,
        (__attribute__((address_space(3))) void*)l, 16, 0, 0);
}

// ---------------- elementwise fp32 -> bf16 hi/lo planes ----------------
__global__ __launch_bounds__(256) void split_f32(const float* __restrict__ x,
                                                 u16* __restrict__ hi,
                                                 u16* __restrict__ lo) {
    size_t i = ((size_t)blockIdx.x * 256 + threadIdx.x) * 8;
    float4 a = *(const float4*)(x + i);
    float4 b = *(const float4*)(x + i + 4);
    float v[8] = {a.x, a.y, a.z, a.w, b.x, b.y, b.z, b.w};
    u16x8 h, l;
#pragma unroll
    for (int u = 0; u < 8; ++u) {
        u16 hb = f2bf(v[u]);
        h[u] = hb;
        l[u] = f2bf(v[u] - bf2f(hb));
    }
    *(u16x8*)(hi + i) = h;
    *(u16x8*)(lo + i) = l;
}

// ---------------- W [K=1024][N=1024] fp32 -> WT hi/lo [N][K] bf16 (x scale) ----------------
__global__ __launch_bounds__(256) void wtrans(const float* __restrict__ W,
                                              u16* __restrict__ Thi,
                                              u16* __restrict__ Tlo,
                                              float scale) {
    const int k0 = blockIdx.x * 64, n0 = blockIdx.y * 64;
    const int t = threadIdx.x;
    __shared__ u16 th[64 * 64];
    __shared__ u16 tl[64 * 64];
#pragma unroll
    for (int rep = 0; rep < 4; ++rep) {
        int kr = (t >> 4) + 16 * rep;
        int nc = (t & 15) * 4;
        float4 v = *(const float4*)(W + (size_t)(k0 + kr) * D_MODEL + n0 + nc);
#pragma unroll
        for (int u = 0; u < 4; ++u) {
            int n = nc + u;
            float x = ((const float*)&v)[u] * scale;
            u16 hb = f2bf(x);
            int a = n * 64 + (kr ^ (8 * ((n >> 3) & 7)));
            th[a] = hb;
            tl[a] = f2bf(x - bf2f(hb));
        }
    }
    __syncthreads();
#pragma unroll
    for (int rep = 0; rep < 2; ++rep) {
        int n = (t >> 3) + 32 * rep;
        int kb = (t & 7) * 8;
        int a = n * 64 + (kb ^ (8 * ((n >> 3) & 7)));
        size_t go = (size_t)(n0 + n) * D_MODEL + k0 + kb;
        *(u16x8*)(Thi + go) = *(const u16x8*)&th[a];
        *(u16x8*)(Tlo + go) = *(const u16x8*)&tl[a];
    }
}

// ---------------- V planes [M][1024] -> Vt planes [B][H][64][S] ----------------
__global__ __launch_bounds__(256) void vtrans(const u16* __restrict__ Vhi,
                                              const u16* __restrict__ Vlo,
                                              u16* __restrict__ Thi,
                                              u16* __restrict__ Tlo) {
    const int b = blockIdx.z, h = blockIdx.y, s0 = blockIdx.x * 64;
    const int t = threadIdx.x;
    __shared__ u16 th[64 * 64];
    __shared__ u16 tl[64 * 64];
#pragma unroll
    for (int rep = 0; rep < 2; ++rep) {
        int s = (t >> 3) + 32 * rep;
        int db = (t & 7) * 8;
        size_t go = (size_t)(b * SEQ + s0 + s) * D_MODEL + h * DHEAD + db;
        u16x8 vh = *(const u16x8*)(Vhi + go);
        u16x8 vl = *(const u16x8*)(Vlo + go);
#pragma unroll
        for (int u = 0; u < 8; ++u) {
            int d = db + u;
            int a = d * 64 + (s ^ (8 * ((d >> 3) & 7)));
            th[a] = vh[u];
            tl[a] = vl[u];
        }
    }
    __syncthreads();
#pragma unroll
    for (int rep = 0; rep < 2; ++rep) {
        int d = (t >> 3) + 32 * rep;
        int sb = (t & 7) * 8;
        int a = d * 64 + (sb ^ (8 * ((d >> 3) & 7)));
        size_t go = ((size_t)((b * NHEAD + h) * DHEAD + d)) * SEQ + s0 + sb;
        *(u16x8*)(Thi + go) = *(const u16x8*)&th[a];
        *(u16x8*)(Tlo + go) = *(const u16x8*)&tl[a];
    }
}

// ---------------- split-bf16 MFMA GEMM: C[M=8192][N=1024] = A @ W (+bias) ----------------
template<int AMODE, int EPI>
__global__ __launch_bounds__(256) void gemm3p(const u16* __restrict__ Ahi,
                                              const u16* __restrict__ Alo,
                                              const float* __restrict__ Af,
                                              const u16* __restrict__ Bhi,
                                              const u16* __restrict__ Blo,
                                              const float* __restrict__ bias,
                                              float* __restrict__ Cf,
                                              u16* __restrict__ Chi,
                                              u16* __restrict__ Clo) {
    const int K = 1024, N = 1024;
    __shared__ u16 sA[2][128 * 32];
    __shared__ u16 sB[2][128 * 32];

    const int t = threadIdx.x;
    const int w = t >> 6, l = t & 63, g = l >> 4, lr = l & 15;
    const int wrow = (w >> 1) * 64, wcol = (w & 1) * 64;

    const int bid = blockIdx.x;
    const int wg = (bid & 7) * 64 + (bid >> 3);
    const int bm = wg >> 3, bn = wg & 7;

    f32x4 acc[4][4];
#pragma unroll
    for (int i = 0; i < 4; ++i)
#pragma unroll
        for (int j = 0; j < 4; ++j) acc[i][j] = (f32x4){0.f, 0.f, 0.f, 0.f};

    const int srow = t >> 2;
    const int scg  = (t & 3) * 8;

    for (int k0 = 0; k0 < K; k0 += 32) {
#pragma unroll
        for (int rep = 0; rep < 2; ++rep) {
            const int row  = srow + 64 * rep;
            const int lofs = row * 32 + scg;
            const size_t ga = (size_t)(bm * 128 + row) * K + k0 + scg;
            if constexpr (AMODE == 0) {
                glds16(Ahi + ga, &sA[0][lofs]);
                glds16(Alo + ga, &sA[1][lofs]);
            } else {
                float4 va = *(const float4*)(Af + ga);
                float4 vb = *(const float4*)(Af + ga + 4);
                float vv[8] = {va.x, va.y, va.z, va.w, vb.x, vb.y, vb.z, vb.w};
                u16x8 hv, lv;
#pragma unroll
                for (int u = 0; u < 8; ++u) {
                    u16 hb = f2bf(vv[u]);
                    hv[u] = hb;
                    lv[u] = f2bf(vv[u] - bf2f(hb));
                }
                *(u16x8*)&sA[0][lofs] = hv;
                *(u16x8*)&sA[1][lofs] = lv;
            }
            const size_t gb = (size_t)(bn * 128 + row) * K + k0 + scg;
            glds16(Bhi + gb, &sB[0][lofs]);
            glds16(Blo + gb, &sB[1][lofs]);
        }
        __syncthreads();

        bf16x8 ah[4], al[4], bh[4], bl[4];
#pragma unroll
        for (int f = 0; f < 4; ++f) {
            const int ra = (wrow + f * 16 + lr) * 32 + 8 * g;
            ah[f] = *(const bf16x8*)&sA[0][ra];
            al[f] = *(const bf16x8*)&sA[1][ra];
            const int rb = (wcol + f * 16 + lr) * 32 + 8 * g;
            bh[f] = *(const bf16x8*)&sB[0][rb];
            bl[f] = *(const bf16x8*)&sB[1][rb];
        }
#pragma unroll
        for (int fi = 0; fi < 4; ++fi)
#pragma unroll
            for (int fj = 0; fj < 4; ++fj) {
                acc[fi][fj] = mfma16(ah[fi], bh[fj], acc[fi][fj]);
                acc[fi][fj] = mfma16(ah[fi], bl[fj], acc[fi][fj]);
                acc[fi][fj] = mfma16(al[fi], bh[fj], acc[fi][fj]);
            }
        __syncthreads();
    }

#pragma unroll
    for (int fj = 0; fj < 4; ++fj) {
        const int colg = bn * 128 + wcol + fj * 16 + lr;
        float bv = 0.f;
        if constexpr (EPI == 0) bv = bias[colg];
#pragma unroll
        for (int fi = 0; fi < 4; ++fi) {
            const int rowb = bm * 128 + wrow + fi * 16 + 4 * g;
#pragma unroll
            for (int j = 0; j < 4; ++j) {
                const float v = acc[fi][fj][j];
                const size_t co = (size_t)(rowb + j) * N + colg;
                if constexpr (EPI == 0) {
                    Cf[co] = v + bv;
                } else {
                    u16 hb = f2bf(v);
                    Chi[co] = hb;
                    Clo[co] = f2bf(v - bf2f(hb));
                }
            }
        }
    }
}

// ---------------- MFMA flash attention, KVT=64, in-register P, defer-rescale ----------------
// 256 thr = 4 waves, 16 q-rows/wave (q = lr), KV tile 64. Scores arrive in log2-units
// (0.125*log2e folded into Wq). S^T = K*Q puts k strips lane-local; pi-permuted Vs
// makes packed P regs feed PV's B operand directly.
__global__ __launch_bounds__(256) void attn_mfma3(const u16* __restrict__ Qhi,
                                                  const u16* __restrict__ Qlo,
                                                  const u16* __restrict__ Khi,
                                                  const u16* __restrict__ Klo,
                                                  const u16* __restrict__ Vthi,
                                                  const u16* __restrict__ Vtlo,
                                                  u16* __restrict__ Ahi,
                                                  u16* __restrict__ Alo) {
    const int b = blockIdx.z, h = blockIdx.y, qt = blockIdx.x;
    const int t = threadIdx.x, w = t >> 6, l = t & 63, g = l >> 4, lr = l & 15;

    __shared__ u16 Ks[2][64 * 64];   // [plane][krow*64 + d'], holds K[r][d' ^ ((r&7)<<3)]
    __shared__ u16 Vs[2][64 * 64];   // [plane][d*64 + slot], pi-permuted, slot ^ ((d&7)<<3)

    const int qrow = qt * 64 + w * 16 + lr;
    const size_t qbase = (size_t)(b * SEQ + qrow) * D_MODEL + h * DHEAD;
    bf16x8 qh[2], ql[2];
#pragma unroll
    for (int c = 0; c < 2; ++c) {
        qh[c] = *(const bf16x8*)(Qhi + qbase + 32 * c + 8 * g);
        ql[c] = *(const bf16x8*)(Qlo + qbase + 32 * c + 8 * g);
    }

    f32x4 o[4];
#pragma unroll
    for (int c = 0; c < 4; ++c) o[c] = (f32x4){0.f, 0.f, 0.f, 0.f};
    float m = -1e30f, lsum = 0.f;

    const u16* Kh = Khi + (size_t)(b * SEQ) * D_MODEL + h * DHEAD;
    const u16* Kl = Klo + (size_t)(b * SEQ) * D_MODEL + h * DHEAD;
    const size_t vbase = (size_t)((b * NHEAD + h) * DHEAD) * SEQ;

    // staging coords (constant per thread)
    const int kr_  = t >> 3;                       // 0..31
    const int kd0  = (t & 7) * 8;
    const int ksrc = kd0 ^ ((kr_ & 7) << 3);       // pre-swizzled global column
    const int klofs = kr_ * 64 + kd0;              // linear LDS dest (= t*8)
    const int vd = t >> 2, vm = t & 3;
    const int vsw = (vd & 7) << 3;
    const int sb = 16 * (vm & 1) + 4 * (vm >> 1);  // pi slot base for k = 8*vm
    const int vrow = vd * 64;

    for (int kv0 = 0; kv0 < SEQ; kv0 += 64) {
        // ---- stage K (64x64, glds, source pre-swizzled -> linear LDS)
        {
            const size_t kg0 = (size_t)(kv0 + kr_) * D_MODEL + ksrc;
            glds16(Kh + kg0, &Ks[0][klofs]);
            glds16(Kl + kg0, &Ks[1][klofs]);
            const size_t kg1 = kg0 + (size_t)32 * D_MODEL;
            glds16(Kh + kg1, &Ks[0][klofs + 2048]);
            glds16(Kl + kg1, &Ks[1][klofs + 2048]);
        }
        // ---- stage V^T (64d x 64k, pi-permuted slots)
        {
            const size_t vg = vbase + (size_t)vd * SEQ + kv0 + 8 * vm;
            u16x8 h0 = *(const u16x8*)(Vthi + vg);
            u16x8 l0 = *(const u16x8*)(Vtlo + vg);
            u16x8 h1 = *(const u16x8*)(Vthi + vg + 32);
            u16x8 l1 = *(const u16x8*)(Vtlo + vg + 32);
            *(u16x4*)&Vs[0][vrow + ((sb)      ^ vsw)] = (u16x4){h0[0], h0[1], h0[2], h0[3]};
            *(u16x4*)&Vs[0][vrow + ((sb +  8) ^ vsw)] = (u16x4){h0[4], h0[5], h0[6], h0[7]};
            *(u16x4*)&Vs[1][vrow + ((sb)      ^ vsw)] = (u16x4){l0[0], l0[1], l0[2], l0[3]};
            *(u16x4*)&Vs[1][vrow + ((sb +  8) ^ vsw)] = (u16x4){l0[4], l0[5], l0[6], l0[7]};
            *(u16x4*)&Vs[0][vrow + ((sb + 32) ^ vsw)] = (u16x4){h1[0], h1[1], h1[2], h1[3]};
            *(u16x4*)&Vs[0][vrow + ((sb + 40) ^ vsw)] = (u16x4){h1[4], h1[5], h1[6], h1[7]};
            *(u16x4*)&Vs[1][vrow + ((sb + 32) ^ vsw)] = (u16x4){l1[0], l1[1], l1[2], l1[3]};
            *(u16x4*)&Vs[1][vrow + ((sb + 40) ^ vsw)] = (u16x4){l1[4], l1[5], l1[6], l1[7]};
        }
        __syncthreads();

        // ---- S^T = K * Q (24 MFMAs): s[rt] holds k = 16rt + 4g + j, q = lr
        f32x4 s[4];
#pragma unroll
        for (int rt = 0; rt < 4; ++rt) s[rt] = (f32x4){0.f, 0.f, 0.f, 0.f};
        const int kkey = (lr & 7) << 3;
#pragma unroll
        for (int rt = 0; rt < 4; ++rt) {
            const int rb = (16 * rt + lr) * 64;
#pragma unroll
            for (int c = 0; c < 2; ++c) {
                const int p = rb + ((8 * g + 32 * c) ^ kkey);
                bf16x8 kh8 = *(const bf16x8*)&Ks[0][p];
                bf16x8 kl8 = *(const bf16x8*)&Ks[1][p];
                s[rt] = mfma16(kh8, qh[c], s[rt]);
                s[rt] = mfma16(kh8, ql[c], s[rt]);
                s[rt] = mfma16(kl8, qh[c], s[rt]);
            }
        }

        // ---- online softmax in log2 units; defer-rescale (THR = 4)
        float pm = fmaxf(fmaxf(fmaxf(s[0][0], s[0][1]), fmaxf(s[0][2], s[0][3])),
                         fmaxf(fmaxf(s[1][0], s[1][1]), fmaxf(s[1][2], s[1][3])));
        pm = fmaxf(pm, fmaxf(fmaxf(fmaxf(s[2][0], s[2][1]), fmaxf(s[2][2], s[2][3])),
                             fmaxf(fmaxf(s[3][0], s[3][1]), fmaxf(s[3][2], s[3][3]))));
        pm = fmaxf(pm, __shfl_xor(pm, 16));
        pm = fmaxf(pm, __shfl_xor(pm, 32));
        if (!__all(pm <= m + 4.f)) {
            const float mn = fmaxf(m, pm);
            const float corr = exp2fast(m - mn);
            m = mn;
            lsum *= corr;
#pragma unroll
            for (int c = 0; c < 4; ++c)
#pragma unroll
                for (int j = 0; j < 4; ++j) o[c][j] *= corr;
        }
        float rs = 0.f;
#pragma unroll
        for (int rt = 0; rt < 4; ++rt)
#pragma unroll
            for (int j = 0; j < 4; ++j) {
                s[rt][j] = exp2fast(s[rt][j] - m);
                rs += s[rt][j];
            }
        rs += __shfl_xor(rs, 16);
        rs += __shfl_xor(rs, 32);
        lsum += rs;

        // ---- P hi/lo pack via v_cvt_pk_bf16_f32 (pi order: elems[0..3]=rt even, [4..7]=rt odd)
        bf16x8 pbh[2], pbl[2];
#pragma unroll
        for (int ks = 0; ks < 2; ++ks) {
            union PW { unsigned w[4]; bf16x8 v; } uh, ul_;
#pragma unroll
            for (int pr = 0; pr < 4; ++pr) {
                const int rt = 2 * ks + (pr >> 1);
                const int j0 = (pr & 1) * 2;
                const float x0 = s[rt][j0], x1 = s[rt][j0 + 1];
                unsigned hp;
                asm("v_cvt_pk_bf16_f32 %0, %1, %2" : "=v"(hp) : "v"(x0), "v"(x1));
                const float r0 = x0 - __uint_as_float(hp << 16);
                const float r1 = x1 - __uint_as_float(hp & 0xffff0000u);
                unsigned lp;
                asm("v_cvt_pk_bf16_f32 %0, %1, %2" : "=v"(lp) : "v"(r0), "v"(r1));
                uh.w[pr] = hp;
                ul_.w[pr] = lp;
            }
            pbh[ks] = uh.v;
            pbl[ks] = ul_.v;
        }

        // ---- O^T += V^T * P^T (24 MFMAs)
#pragma unroll
        for (int ks = 0; ks < 2; ++ks)
#pragma unroll
            for (int c = 0; c < 4; ++c) {
                const int dv = 16 * c + lr;
                const int vp = dv * 64 + ((8 * g + 32 * ks) ^ ((dv & 7) << 3));
                bf16x8 vbh = *(const bf16x8*)&Vs[0][vp];
                bf16x8 vbl = *(const bf16x8*)&Vs[1][vp];
                o[c] = mfma16(vbh, pbh[ks], o[c]);
                o[c] = mfma16(vbl, pbh[ks], o[c]);
                o[c] = mfma16(vbh, pbl[ks], o[c]);
            }
        __syncthreads();
    }

    // ---- epilogue: lane q = lr, d = 16c + 4g + j -> split bf16 planes
    const float inv = 1.f / lsum;
#pragma unroll
    for (int c = 0; c < 4; ++c) {
        u16x4 hv, lv;
#pragma unroll
        for (int j = 0; j < 4; ++j) {
            const float v = o[c][j] * inv;
            const u16 hb = f2bf(v);
            hv[j] = hb;
            lv[j] = f2bf(v - bf2f(hb));
        }
        const size_t ao = qbase + 16 * c + 4 * g;
        *(u16x4*)(Ahi + ao) = hv;
        *(u16x4*)(Alo + ao) = lv;
    }
}

// ---------------- launch ----------------
extern "C" void kernel_launch(void* const* d_in, const int* in_sizes, int n_in,
                              void* d_out, int out_size, void* d_ws, size_t ws_size,
                              hipStream_t stream) {
    const float* inputs  = (const float*)d_in[0];
    const float* context = (const float*)d_in[1];
    const float* Wq      = (const float*)d_in[2];
    const float* Wk      = (const float*)d_in[3];
    const float* Wv      = (const float*)d_in[4];
    const float* Wo      = (const float*)d_in[5];
    const float* bo      = (const float*)d_in[6];
    float* out = (float*)d_out;

    const size_t P  = (size_t)MROWS * D_MODEL;      // 8388608 elems
    const size_t WP = (size_t)D_MODEL * D_MODEL;

    u16* base = (u16*)d_ws;
    u16* r0 = base;                 // Ctx hi/lo -> Vt hi/lo
    u16* r1 = base + 2 * P;         // K hi/lo
    u16* r2 = base + 4 * P;         // V hi/lo -> Q hi/lo -> A hi/lo
    u16* wt = base + 6 * P;
    u16 *wkh = wt,          *wkl = wt + WP;
    u16 *wvh = wt + 2 * WP, *wvl = wt + 3 * WP;
    u16 *wqh = wt + 4 * WP, *wql = wt + 5 * WP;
    u16 *woh = wt + 6 * WP, *wol = wt + 7 * WP;

    u16 *ctxh = r0, *ctxl = r0 + P;
    u16 *vth  = r0, *vtl  = r0 + P;
    u16 *kh   = r1, *kl   = r1 + P;
    u16 *vh   = r2, *vl   = r2 + P;
    u16 *qh   = r2, *ql   = r2 + P;
    u16 *ah   = r2, *al   = r2 + P;

    dim3 tb(256);
    dim3 wg_grid(16, 16);

    const float QSCALE = 0.18033688011112042f;   // 0.125 * log2(e)

    wtrans<<<wg_grid, tb, 0, stream>>>(Wk, wkh, wkl, 1.0f);
    wtrans<<<wg_grid, tb, 0, stream>>>(Wv, wvh, wvl, 1.0f);
    wtrans<<<wg_grid, tb, 0, stream>>>(Wq, wqh, wql, QSCALE);
    wtrans<<<wg_grid, tb, 0, stream>>>(Wo, woh, wol, 1.0f);

    split_f32<<<dim3(P / (256 * 8)), tb, 0, stream>>>(context, ctxh, ctxl);

    gemm3p<0, 1><<<dim3(512), tb, 0, stream>>>(ctxh, ctxl, nullptr, wkh, wkl,
                                               nullptr, nullptr, kh, kl);
    gemm3p<0, 1><<<dim3(512), tb, 0, stream>>>(ctxh, ctxl, nullptr, wvh, wvl,
                                               nullptr, nullptr, vh, vl);

    vtrans<<<dim3(SEQ / 64, NHEAD, BATCH), tb, 0, stream>>>(vh, vl, vth, vtl);

    gemm3p<1, 1><<<dim3(512), tb, 0, stream>>>(nullptr, nullptr, inputs, wqh, wql,
                                               nullptr, nullptr, qh, ql);

    attn_mfma3<<<dim3(SEQ / 64, NHEAD, BATCH), tb, 0, stream>>>(qh, ql, kh, kl,
                                                                vth, vtl, ah, al);

    gemm3p<0, 0><<<dim3(512), tb, 0, stream>>>(ah, al, nullptr, woh, wol,
                                               bo, out, nullptr, nullptr);
}

// Round 6
// 483.306 us; speedup vs baseline: 5.5348x; 1.1153x over previous
//
#include <hip/hip_runtime.h>
#include <hip/hip_bf16.h>

// CrossAttention — B=4, Sq=Skv=2048, D=1024, H=16, Dh=64, fp32 in/out.
// Round 6: attention LDS-byte diet — 32 q-rows/wave (2x K/V LDS reuse),
//          V staged via global_load_lds from a pre-permuted global image
//          (no ds_writes), double-buffered K/V with overlap pipeline,
//          XCD-chunked grid for KV L2 locality.

#define D_MODEL 1024
#define NHEAD   16
#define DHEAD   64
#define BATCH   4
#define SEQ     2048
#define MROWS   (BATCH * SEQ)   // 8192

typedef unsigned short u16;
typedef __attribute__((ext_vector_type(8))) short          bf16x8;
typedef __attribute__((ext_vector_type(4))) float          f32x4;
typedef __attribute__((ext_vector_type(8))) unsigned short u16x8;
typedef __attribute__((ext_vector_type(4))) unsigned short u16x4;

__device__ __forceinline__ u16 f2bf(float x) {          // RNE f32 -> bf16
    unsigned u = __float_as_uint(x);
    u += 0x7fffu + ((u >> 16) & 1u);
    return (u16)(u >> 16);
}
__device__ __forceinline__ float bf2f(u16 h) { return __uint_as_float(((unsigned)h) << 16); }

__device__ __forceinline__ f32x4 mfma16(bf16x8 a, bf16x8 b, f32x4 c) {
    return __builtin_amdgcn_mfma_f32_16x16x32_bf16(a, b, c, 0, 0, 0);
}

__device__ __forceinline__ float exp2fast(float x) {    // D = 2^S0
    float r;
    asm("v_exp_f32 %0, %1" : "=v"(r) : "v"(x));
    return r;
}

// async global->LDS, 16B per lane; LDS dest = wave base + lane*16 (linear)
__device__ __forceinline__ void glds16(const void* g, void* l) {
    __builtin_amdgcn_global_load_lds(
        (const __attribute__((address_space(1))) void*)g,
        (__attribute__((address_space(3))) void*)l, 16, 0, 0);
}

// ---------------- elementwise fp32 -> bf16 hi/lo planes ----------------
__global__ __launch_bounds__(256) void split_f32(const float* __restrict__ x,
                                                 u16* __restrict__ hi,
                                                 u16* __restrict__ lo) {
    size_t i = ((size_t)blockIdx.x * 256 + threadIdx.x) * 8;
    float4 a = *(const float4*)(x + i);
    float4 b = *(const float4*)(x + i + 4);
    float v[8] = {a.x, a.y, a.z, a.w, b.x, b.y, b.z, b.w};
    u16x8 h, l;
#pragma unroll
    for (int u = 0; u < 8; ++u) {
        u16 hb = f2bf(v[u]);
        h[u] = hb;
        l[u] = f2bf(v[u] - bf2f(hb));
    }
    *(u16x8*)(hi + i) = h;
    *(u16x8*)(lo + i) = l;
}

// ---------------- W [K=1024][N=1024] fp32 -> WT hi/lo [N][K] bf16 (x scale) ----------------
__global__ __launch_bounds__(256) void wtrans(const float* __restrict__ W,
                                              u16* __restrict__ Thi,
                                              u16* __restrict__ Tlo,
                                              float scale) {
    const int k0 = blockIdx.x * 64, n0 = blockIdx.y * 64;
    const int t = threadIdx.x;
    __shared__ u16 th[64 * 64];
    __shared__ u16 tl[64 * 64];
#pragma unroll
    for (int rep = 0; rep < 4; ++rep) {
        int kr = (t >> 4) + 16 * rep;
        int nc = (t & 15) * 4;
        float4 v = *(const float4*)(W + (size_t)(k0 + kr) * D_MODEL + n0 + nc);
#pragma unroll
        for (int u = 0; u < 4; ++u) {
            int n = nc + u;
            float x = ((const float*)&v)[u] * scale;
            u16 hb = f2bf(x);
            int a = n * 64 + (kr ^ (8 * ((n >> 3) & 7)));
            th[a] = hb;
            tl[a] = f2bf(x - bf2f(hb));
        }
    }
    __syncthreads();
#pragma unroll
    for (int rep = 0; rep < 2; ++rep) {
        int n = (t >> 3) + 32 * rep;
        int kb = (t & 7) * 8;
        int a = n * 64 + (kb ^ (8 * ((n >> 3) & 7)));
        size_t go = (size_t)(n0 + n) * D_MODEL + k0 + kb;
        *(u16x8*)(Thi + go) = *(const u16x8*)&th[a];
        *(u16x8*)(Tlo + go) = *(const u16x8*)&tl[a];
    }
}

// ---------------- V planes [M][1024] -> glds-ready image planes ----------------
// Image: [B][H][tile=S/64][d=0..63][p=0..63] where content at (d,p) is
// V[s = kv0 + kfn((p) ^ ((d&7)<<3))][h*64+d],  kfn(8q'+i) = ka(q') + (i>>2)*16 + (i&3),
// ka(q') = (q'&3)*4 + (q'>>2)*32.   This is exactly the LDS image attention's PV expects.
__global__ __launch_bounds__(256) void vtrans2(const u16* __restrict__ Vhi,
                                               const u16* __restrict__ Vlo,
                                               u16* __restrict__ Ph,
                                               u16* __restrict__ Pl) {
    const int b = blockIdx.z, h = blockIdx.y, s0 = blockIdx.x * 64;
    const int t = threadIdx.x;
    __shared__ u16 th[64 * 64];
    __shared__ u16 tl[64 * 64];
#pragma unroll
    for (int rep = 0; rep < 2; ++rep) {
        int s = (t >> 3) + 32 * rep;
        int db = (t & 7) * 8;
        size_t go = (size_t)(b * SEQ + s0 + s) * D_MODEL + h * DHEAD + db;
        u16x8 vh = *(const u16x8*)(Vhi + go);
        u16x8 vl = *(const u16x8*)(Vlo + go);
#pragma unroll
        for (int u = 0; u < 8; ++u) {
            int d = db + u;
            int a = d * 64 + (s ^ (8 * ((d >> 3) & 7)));
            th[a] = vh[u];
            tl[a] = vl[u];
        }
    }
    __syncthreads();
    const size_t tbase = ((size_t)((b * NHEAD + h) * 32) + (s0 >> 6)) * 4096;
#pragma unroll
    for (int rep = 0; rep < 2; ++rep) {
        int idx = t + 256 * rep;      // 0..511
        int d = idx >> 3, q = idx & 7;
        int qp = q ^ (d & 7);
        int ka = (qp & 3) * 4 + (qp >> 2) * 32;
        int kb = ka + 16;
        int swin = 8 * ((d >> 3) & 7);
        u16x8 oh, ol;
        u16x4 a0 = *(const u16x4*)&th[d * 64 + (ka ^ swin)];
        u16x4 a1 = *(const u16x4*)&th[d * 64 + (kb ^ swin)];
        u16x4 b0 = *(const u16x4*)&tl[d * 64 + (ka ^ swin)];
        u16x4 b1 = *(const u16x4*)&tl[d * 64 + (kb ^ swin)];
#pragma unroll
        for (int i = 0; i < 4; ++i) {
            oh[i] = a0[i]; oh[4 + i] = a1[i];
            ol[i] = b0[i]; ol[4 + i] = b1[i];
        }
        size_t go = tbase + d * 64 + 8 * q;
        *(u16x8*)(Ph + go) = oh;
        *(u16x8*)(Pl + go) = ol;
    }
}

// ---------------- split-bf16 MFMA GEMM: C[M=8192][N=1024] = A @ W (+bias) ----------------
template<int AMODE, int EPI>
__global__ __launch_bounds__(256) void gemm3p(const u16* __restrict__ Ahi,
                                              const u16* __restrict__ Alo,
                                              const float* __restrict__ Af,
                                              const u16* __restrict__ Bhi,
                                              const u16* __restrict__ Blo,
                                              const float* __restrict__ bias,
                                              float* __restrict__ Cf,
                                              u16* __restrict__ Chi,
                                              u16* __restrict__ Clo) {
    const int K = 1024, N = 1024;
    __shared__ u16 sA[2][128 * 32];
    __shared__ u16 sB[2][128 * 32];

    const int t = threadIdx.x;
    const int w = t >> 6, l = t & 63, g = l >> 4, lr = l & 15;
    const int wrow = (w >> 1) * 64, wcol = (w & 1) * 64;

    const int bid = blockIdx.x;
    const int wg = (bid & 7) * 64 + (bid >> 3);
    const int bm = wg >> 3, bn = wg & 7;

    f32x4 acc[4][4];
#pragma unroll
    for (int i = 0; i < 4; ++i)
#pragma unroll
        for (int j = 0; j < 4; ++j) acc[i][j] = (f32x4){0.f, 0.f, 0.f, 0.f};

    const int srow = t >> 2;
    const int scg  = (t & 3) * 8;

    for (int k0 = 0; k0 < K; k0 += 32) {
#pragma unroll
        for (int rep = 0; rep < 2; ++rep) {
            const int row  = srow + 64 * rep;
            const int lofs = row * 32 + scg;
            const size_t ga = (size_t)(bm * 128 + row) * K + k0 + scg;
            if constexpr (AMODE == 0) {
                glds16(Ahi + ga, &sA[0][lofs]);
                glds16(Alo + ga, &sA[1][lofs]);
            } else {
                float4 va = *(const float4*)(Af + ga);
                float4 vb = *(const float4*)(Af + ga + 4);
                float vv[8] = {va.x, va.y, va.z, va.w, vb.x, vb.y, vb.z, vb.w};
                u16x8 hv, lv;
#pragma unroll
                for (int u = 0; u < 8; ++u) {
                    u16 hb = f2bf(vv[u]);
                    hv[u] = hb;
                    lv[u] = f2bf(vv[u] - bf2f(hb));
                }
                *(u16x8*)&sA[0][lofs] = hv;
                *(u16x8*)&sA[1][lofs] = lv;
            }
            const size_t gb = (size_t)(bn * 128 + row) * K + k0 + scg;
            glds16(Bhi + gb, &sB[0][lofs]);
            glds16(Blo + gb, &sB[1][lofs]);
        }
        __syncthreads();

        bf16x8 ah[4], al[4], bh[4], bl[4];
#pragma unroll
        for (int f = 0; f < 4; ++f) {
            const int ra = (wrow + f * 16 + lr) * 32 + 8 * g;
            ah[f] = *(const bf16x8*)&sA[0][ra];
            al[f] = *(const bf16x8*)&sA[1][ra];
            const int rb = (wcol + f * 16 + lr) * 32 + 8 * g;
            bh[f] = *(const bf16x8*)&sB[0][rb];
            bl[f] = *(const bf16x8*)&sB[1][rb];
        }
#pragma unroll
        for (int fi = 0; fi < 4; ++fi)
#pragma unroll
            for (int fj = 0; fj < 4; ++fj) {
                acc[fi][fj] = mfma16(ah[fi], bh[fj], acc[fi][fj]);
                acc[fi][fj] = mfma16(ah[fi], bl[fj], acc[fi][fj]);
                acc[fi][fj] = mfma16(al[fi], bh[fj], acc[fi][fj]);
            }
        __syncthreads();
    }

#pragma unroll
    for (int fj = 0; fj < 4; ++fj) {
        const int colg = bn * 128 + wcol + fj * 16 + lr;
        float bv = 0.f;
        if constexpr (EPI == 0) bv = bias[colg];
#pragma unroll
        for (int fi = 0; fi < 4; ++fi) {
            const int rowb = bm * 128 + wrow + fi * 16 + 4 * g;
#pragma unroll
            for (int j = 0; j < 4; ++j) {
                const float v = acc[fi][fj][j];
                const size_t co = (size_t)(rowb + j) * N + colg;
                if constexpr (EPI == 0) {
                    Cf[co] = v + bv;
                } else {
                    u16 hb = f2bf(v);
                    Chi[co] = hb;
                    Clo[co] = f2bf(v - bf2f(hb));
                }
            }
        }
    }
}

// ---------------- MFMA flash attention: QT=128, 32 q/wave, dbuf glds staging ----------------
__global__ __launch_bounds__(256) void attn_mfma4(const u16* __restrict__ Qhi,
                                                  const u16* __restrict__ Qlo,
                                                  const u16* __restrict__ Khi,
                                                  const u16* __restrict__ Klo,
                                                  const u16* __restrict__ Vph,
                                                  const u16* __restrict__ Vpl,
                                                  u16* __restrict__ Ahi,
                                                  u16* __restrict__ Alo) {
    // XCD-chunked decode: 1024 blocks, 8 XCDs, 128/chunk = 8 (b,h) x 16 q-tiles
    const int bid  = blockIdx.x;
    const int wgid = (bid & 7) * 128 + (bid >> 3);
    const int qt = wgid & 15;
    const int hb = wgid >> 4;
    const int h = hb & 15, b = hb >> 4;

    const int t = threadIdx.x, w = t >> 6, l = t & 63, g = l >> 4, lr = l & 15;

    __shared__ u16 Ks[2][2][4096];   // [buf][plane][r*64 + d'], content K[r][d'^((r&7)<<3)]
    __shared__ u16 Vs[2][2][4096];   // [buf][plane][d*64 + p],  pre-permuted image

    // ---- Q frags in registers: q = qt*128 + w*32 + qg*16 + lr
    bf16x8 qh[2][2], ql[2][2];
#pragma unroll
    for (int qg = 0; qg < 2; ++qg) {
        const size_t qb = (size_t)(b * SEQ + qt * 128 + w * 32 + qg * 16 + lr) * D_MODEL + h * DHEAD;
#pragma unroll
        for (int c = 0; c < 2; ++c) {
            qh[qg][c] = *(const bf16x8*)(Qhi + qb + 32 * c + 8 * g);
            ql[qg][c] = *(const bf16x8*)(Qlo + qb + 32 * c + 8 * g);
        }
    }

    f32x4 o[2][4];
#pragma unroll
    for (int qg = 0; qg < 2; ++qg)
#pragma unroll
        for (int c = 0; c < 4; ++c) o[qg][c] = (f32x4){0.f, 0.f, 0.f, 0.f};
    float m[2] = {-1e30f, -1e30f}, lsum[2] = {0.f, 0.f};

    const u16* Kh = Khi + (size_t)(b * SEQ) * D_MODEL + h * DHEAD;
    const u16* Kl = Klo + (size_t)(b * SEQ) * D_MODEL + h * DHEAD;
    const size_t vtb = (size_t)((b * NHEAD + h) * 32) * 4096;

    // staging coords
    const int kr_ = t >> 3, kd0 = (t & 7) * 8;
    const int ksrc  = kd0 ^ ((kr_ & 7) << 3);   // pre-swizzled source column
    const int klofs = t * 8;                    // linear LDS dest
    const int kkey  = (lr & 7) << 3;

    auto stage = [&](int bb, int kv0) {
        const size_t kg0 = (size_t)(kv0 + kr_) * D_MODEL + ksrc;
        glds16(Kh + kg0, &Ks[bb][0][klofs]);
        glds16(Kl + kg0, &Ks[bb][1][klofs]);
        const size_t kg1 = kg0 + (size_t)32 * D_MODEL;
        glds16(Kh + kg1, &Ks[bb][0][klofs + 2048]);
        glds16(Kl + kg1, &Ks[bb][1][klofs + 2048]);
        const size_t vg = vtb + (size_t)(kv0 >> 6) * 4096 + (size_t)t * 8;
        glds16(Vph + vg,        &Vs[bb][0][klofs]);
        glds16(Vph + vg + 2048, &Vs[bb][0][klofs + 2048]);
        glds16(Vpl + vg,        &Vs[bb][1][klofs]);
        glds16(Vpl + vg + 2048, &Vs[bb][1][klofs + 2048]);
    };

    stage(0, 0);

    for (int it = 0; it < SEQ / 64; ++it) {
        const int cb = it & 1;
        __syncthreads();                          // tile it ready; buf cb^1 free
        if (it < SEQ / 64 - 1) stage(cb ^ 1, (it + 1) << 6);

        // ---- S^T = K * Q: s[qg][rt] holds k = 16rt+4g+j, q = qg*16+lr
        f32x4 s[2][4];
#pragma unroll
        for (int qg = 0; qg < 2; ++qg)
#pragma unroll
            for (int rt = 0; rt < 4; ++rt) s[qg][rt] = (f32x4){0.f, 0.f, 0.f, 0.f};
#pragma unroll
        for (int rt = 0; rt < 4; ++rt) {
            const int rb = (16 * rt + lr) * 64;
#pragma unroll
            for (int c = 0; c < 2; ++c) {
                const int p = rb + ((8 * g + 32 * c) ^ kkey);
                bf16x8 kh8 = *(const bf16x8*)&Ks[cb][0][p];
                bf16x8 kl8 = *(const bf16x8*)&Ks[cb][1][p];
#pragma unroll
                for (int qg = 0; qg < 2; ++qg) {
                    s[qg][rt] = mfma16(kh8, qh[qg][c], s[qg][rt]);
                    s[qg][rt] = mfma16(kh8, ql[qg][c], s[qg][rt]);
                    s[qg][rt] = mfma16(kl8, qh[qg][c], s[qg][rt]);
                }
            }
        }

        // ---- online softmax (log2 units) + in-register P pack, per qg
        bf16x8 pbh[2][2], pbl[2][2];
#pragma unroll
        for (int qg = 0; qg < 2; ++qg) {
            float pm = s[qg][0][0];
#pragma unroll
            for (int rt = 0; rt < 4; ++rt)
#pragma unroll
                for (int j = 0; j < 4; ++j) pm = fmaxf(pm, s[qg][rt][j]);
            pm = fmaxf(pm, __shfl_xor(pm, 16));
            pm = fmaxf(pm, __shfl_xor(pm, 32));
            if (!__all(pm <= m[qg] + 4.f)) {
                const float mn = fmaxf(m[qg], pm);
                const float corr = exp2fast(m[qg] - mn);
                m[qg] = mn;
                lsum[qg] *= corr;
#pragma unroll
                for (int c = 0; c < 4; ++c)
#pragma unroll
                    for (int j = 0; j < 4; ++j) o[qg][c][j] *= corr;
            }
            float rs = 0.f;
#pragma unroll
            for (int rt = 0; rt < 4; ++rt)
#pragma unroll
                for (int j = 0; j < 4; ++j) {
                    s[qg][rt][j] = exp2fast(s[qg][rt][j] - m[qg]);
                    rs += s[qg][rt][j];
                }
            rs += __shfl_xor(rs, 16);
            rs += __shfl_xor(rs, 32);
            lsum[qg] += rs;

#pragma unroll
            for (int ks = 0; ks < 2; ++ks) {
                union PW { unsigned u[4]; bf16x8 v; } uh, ul_;
#pragma unroll
                for (int pr = 0; pr < 4; ++pr) {
                    const int rt = 2 * ks + (pr >> 1);
                    const int j0 = (pr & 1) * 2;
                    const float x0 = s[qg][rt][j0], x1 = s[qg][rt][j0 + 1];
                    unsigned hp;
                    asm("v_cvt_pk_bf16_f32 %0, %1, %2" : "=v"(hp) : "v"(x0), "v"(x1));
                    const float r0 = x0 - __uint_as_float(hp << 16);
                    const float r1 = x1 - __uint_as_float(hp & 0xffff0000u);
                    unsigned lp;
                    asm("v_cvt_pk_bf16_f32 %0, %1, %2" : "=v"(lp) : "v"(r0), "v"(r1));
                    uh.u[pr] = hp;
                    ul_.u[pr] = lp;
                }
                pbh[qg][ks] = uh.v;
                pbl[qg][ks] = ul_.v;
            }
        }

        // ---- O^T += V^T * P^T
#pragma unroll
        for (int ks = 0; ks < 2; ++ks)
#pragma unroll
            for (int c = 0; c < 4; ++c) {
                const int vp = (16 * c + lr) * 64 + ((8 * g + 32 * ks) ^ kkey);
                bf16x8 vbh = *(const bf16x8*)&Vs[cb][0][vp];
                bf16x8 vbl = *(const bf16x8*)&Vs[cb][1][vp];
#pragma unroll
                for (int qg = 0; qg < 2; ++qg) {
                    o[qg][c] = mfma16(vbh, pbh[qg][ks], o[qg][c]);
                    o[qg][c] = mfma16(vbl, pbh[qg][ks], o[qg][c]);
                    o[qg][c] = mfma16(vbh, pbl[qg][ks], o[qg][c]);
                }
            }
    }

    // ---- epilogue: lane q = qg*16+lr, d = 16c+4g+j -> split bf16 planes
#pragma unroll
    for (int qg = 0; qg < 2; ++qg) {
        const float inv = 1.f / lsum[qg];
        const size_t ab = (size_t)(b * SEQ + qt * 128 + w * 32 + qg * 16 + lr) * D_MODEL + h * DHEAD;
#pragma unroll
        for (int c = 0; c < 4; ++c) {
            u16x4 hv, lv;
#pragma unroll
            for (int j = 0; j < 4; ++j) {
                const float v = o[qg][c][j] * inv;
                const u16 hb = f2bf(v);
                hv[j] = hb;
                lv[j] = f2bf(v - bf2f(hb));
            }
            *(u16x4*)(Ahi + ab + 16 * c + 4 * g) = hv;
            *(u16x4*)(Alo + ab + 16 * c + 4 * g) = lv;
        }
    }
}

// ---------------- launch ----------------
extern "C" void kernel_launch(void* const* d_in, const int* in_sizes, int n_in,
                              void* d_out, int out_size, void* d_ws, size_t ws_size,
                              hipStream_t stream) {
    const float* inputs  = (const float*)d_in[0];
    const float* context = (const float*)d_in[1];
    const float* Wq      = (const float*)d_in[2];
    const float* Wk      = (const float*)d_in[3];
    const float* Wv      = (const float*)d_in[4];
    const float* Wo      = (const float*)d_in[5];
    const float* bo      = (const float*)d_in[6];
    float* out = (float*)d_out;

    const size_t P  = (size_t)MROWS * D_MODEL;      // 8388608 elems
    const size_t WP = (size_t)D_MODEL * D_MODEL;

    u16* base = (u16*)d_ws;
    u16* r0 = base;                 // Ctx hi/lo -> Vp image hi/lo
    u16* r1 = base + 2 * P;         // K hi/lo
    u16* r2 = base + 4 * P;         // V hi/lo -> Q hi/lo -> A hi/lo
    u16* wt = base + 6 * P;
    u16 *wkh = wt,          *wkl = wt + WP;
    u16 *wvh = wt + 2 * WP, *wvl = wt + 3 * WP;
    u16 *wqh = wt + 4 * WP, *wql = wt + 5 * WP;
    u16 *woh = wt + 6 * WP, *wol = wt + 7 * WP;

    u16 *ctxh = r0, *ctxl = r0 + P;
    u16 *vph  = r0, *vpl  = r0 + P;   // V image planes (after ctx dead)
    u16 *kh   = r1, *kl   = r1 + P;
    u16 *vh   = r2, *vl   = r2 + P;
    u16 *qh   = r2, *ql   = r2 + P;   // Q over V (V dead after vtrans2)
    u16 *ah   = r2, *al   = r2 + P;   // attn A over Q (read-before-write per block)

    dim3 tb(256);
    dim3 wg_grid(16, 16);

    const float QSCALE = 0.18033688011112042f;   // 0.125 * log2(e)

    wtrans<<<wg_grid, tb, 0, stream>>>(Wk, wkh, wkl, 1.0f);
    wtrans<<<wg_grid, tb, 0, stream>>>(Wv, wvh, wvl, 1.0f);
    wtrans<<<wg_grid, tb, 0, stream>>>(Wq, wqh, wql, QSCALE);
    wtrans<<<wg_grid, tb, 0, stream>>>(Wo, woh, wol, 1.0f);

    split_f32<<<dim3(P / (256 * 8)), tb, 0, stream>>>(context, ctxh, ctxl);

    gemm3p<0, 1><<<dim3(512), tb, 0, stream>>>(ctxh, ctxl, nullptr, wkh, wkl,
                                               nullptr, nullptr, kh, kl);
    gemm3p<0, 1><<<dim3(512), tb, 0, stream>>>(ctxh, ctxl, nullptr, wvh, wvl,
                                               nullptr, nullptr, vh, vl);

    vtrans2<<<dim3(SEQ / 64, NHEAD, BATCH), tb, 0, stream>>>(vh, vl, vph, vpl);

    gemm3p<1, 1><<<dim3(512), tb, 0, stream>>>(nullptr, nullptr, inputs, wqh, wql,
                                               nullptr, nullptr, qh, ql);

    attn_mfma4<<<dim3(1024), tb, 0, stream>>>(qh, ql, kh, kl, vph, vpl, ah, al);

    gemm3p<0, 0><<<dim3(512), tb, 0, stream>>>(ah, al, nullptr, woh, wol,
                                               bo, out, nullptr, nullptr);
}